// Round 2
// baseline (2547.959 us; speedup 1.0000x reference)
//
#include <hip/hip_runtime.h>
#include <math.h>

// Problem constants
#define T_LEN 512
#define B_SZ  32
#define NHEAD 8
#define DHEAD 64
#define H_DIM 512
#define TBTOK 16384          // T*B
#define DKEY  640
#define DVAL  1152
#define P_DIM 1152

// ---------------------------------------------------------------------------
// Embedding / gather:
//   pred[:,512:1152] = [questions(128)|subjects(256)|ca(256)]   (= query)
//   labans[:,0:512]  = [lab(256)|ans(256)]                      (value head)
// value = [lab|ans|ca|questions|subjects] is reconstructed inside the V GEMM.
// ---------------------------------------------------------------------------
__global__ __launch_bounds__(256) void embed_kernel(
    const int* __restrict__ ans, const int* __restrict__ cans,
    const int* __restrict__ labels, const float* __restrict__ mask,
    const int* __restrict__ qids, const int* __restrict__ sids,
    const float* __restrict__ smask,
    const float* __restrict__ Eq, const float* __restrict__ Es,
    const float* __restrict__ Ea, const float* __restrict__ El,
    float* __restrict__ pred, float* __restrict__ labans)
{
    int m = blockIdx.x;              // token = t*B + b
    int tid = threadIdx.x;           // 256
    float mval = mask[m];
    int qid = qids[m];
    int a   = ans[m] - 1;
    int ca  = cans[m] - 1;
    int lb  = labels[m];
    float* pr = pred   + (size_t)m * P_DIM;
    float* vr = labans + (size_t)m * 512;

    // questions (128)
    if (tid < 128) {
        pr[512 + tid] = Eq[(size_t)qid * 128 + tid];
    }
    int d = tid;                     // 0..255
    // subjects (sum of 8 masked rows of Es)
    float s = 0.f;
#pragma unroll
    for (int j = 0; j < 8; j++) {
        int  sid = sids[m * 8 + j];
        float sm = smask[m * 8 + j];
        s += Es[(size_t)sid * 256 + d] * sm;
    }
    pr[640 + d] = s;
    pr[896 + d] = Ea[ca * 256 + d];
    vr[0   + d] = El[lb * 256 + d] * mval;
    vr[256 + d] = Ea[a  * 256 + d] * mval;
}

// ---------------------------------------------------------------------------
// Generic fp32 GEMM: C(M x N) = A(M x K) @ W(N x K)^T + bias
// MODE 0: plain store  MODE 1: relu store  MODE 2: scatter to (B,NH,T,DH)
// MODE 3: no store; relu then fused dot with OW, atomicAdd into lg[row]
// VMAP: A cols 0..511 from A (stride 512), 512..767 -> A2 col k+384 (ca),
//       768..1151 -> A2 col k-256 (questions|subjects); A2 stride 1152.
// grid = (M/64, N/64), 256 threads, 64x64 tile, 4x4 per thread, K-tile 32.
// ---------------------------------------------------------------------------
template<int MODE, bool VMAP>
__global__ __launch_bounds__(256) void gemm_nt(
    const float* __restrict__ A, int lda,
    const float* __restrict__ A2,
    const float* __restrict__ W, int ldw,
    const float* __restrict__ bias,
    float* __restrict__ C, int ldc, int K,
    const float* __restrict__ OW, float* __restrict__ lg)
{
    __shared__ __align__(16) float As[32][68];
    __shared__ __align__(16) float Ws[32][68];

    const int m0 = blockIdx.x * 64;
    const int n0 = blockIdx.y * 64;
    const int tid = threadIdx.x;
    const int tm = tid >> 4;         // 0..15
    const int tn = tid & 15;         // 0..15
    const int lr = tid >> 2;         // loader row 0..63
    const int lk = (tid & 3) * 8;    // 0,8,16,24

    float acc[4][4] = {};
    const float* Wp = W + (size_t)(n0 + lr) * ldw + lk;

    for (int k0 = 0; k0 < K; k0 += 32) {
        const float* ap;
        if (VMAP) {
            int kk = k0 + lk;
            if (kk < 512)      ap = A  + (size_t)(m0 + lr) * 512  + kk;
            else if (kk < 768) ap = A2 + (size_t)(m0 + lr) * 1152 + kk + 384;
            else               ap = A2 + (size_t)(m0 + lr) * 1152 + kk - 256;
        } else {
            ap = A + (size_t)(m0 + lr) * lda + k0 + lk;
        }
        float4 a0 = *(const float4*)ap;
        float4 a1 = *(const float4*)(ap + 4);
        float4 w0 = *(const float4*)(Wp + k0);
        float4 w1 = *(const float4*)(Wp + k0 + 4);
        As[lk+0][lr]=a0.x; As[lk+1][lr]=a0.y; As[lk+2][lr]=a0.z; As[lk+3][lr]=a0.w;
        As[lk+4][lr]=a1.x; As[lk+5][lr]=a1.y; As[lk+6][lr]=a1.z; As[lk+7][lr]=a1.w;
        Ws[lk+0][lr]=w0.x; Ws[lk+1][lr]=w0.y; Ws[lk+2][lr]=w0.z; Ws[lk+3][lr]=w0.w;
        Ws[lk+4][lr]=w1.x; Ws[lk+5][lr]=w1.y; Ws[lk+6][lr]=w1.z; Ws[lk+7][lr]=w1.w;
        __syncthreads();
#pragma unroll
        for (int kk = 0; kk < 32; kk++) {
            float4 av = *(const float4*)&As[kk][tm << 2];
            float4 wv = *(const float4*)&Ws[kk][tn << 2];
            float a4[4] = {av.x, av.y, av.z, av.w};
            float w4[4] = {wv.x, wv.y, wv.z, wv.w};
#pragma unroll
            for (int i = 0; i < 4; i++)
#pragma unroll
                for (int j = 0; j < 4; j++)
                    acc[i][j] = fmaf(a4[i], w4[j], acc[i][j]);
        }
        __syncthreads();
    }

    if (MODE == 3) {
        float part[4] = {0.f, 0.f, 0.f, 0.f};
#pragma unroll
        for (int i = 0; i < 4; i++)
#pragma unroll
            for (int j = 0; j < 4; j++) {
                int col = n0 + (tn << 2) + j;
                float v = fmaxf(acc[i][j] + bias[col], 0.f);
                part[i] = fmaf(v, OW[col], part[i]);
            }
#pragma unroll
        for (int i = 0; i < 4; i++) {
#pragma unroll
            for (int off = 1; off < 16; off <<= 1)
                part[i] += __shfl_xor(part[i], off, 64);
        }
        if (tn == 0) {
#pragma unroll
            for (int i = 0; i < 4; i++)
                atomicAdd(&lg[m0 + (tm << 2) + i], part[i]);
        }
        return;
    }

#pragma unroll
    for (int i = 0; i < 4; i++) {
        int row = m0 + (tm << 2) + i;
#pragma unroll
        for (int j = 0; j < 4; j++) {
            int col = n0 + (tn << 2) + j;
            float v = acc[i][j] + bias[col];
            if (MODE == 1) v = fmaxf(v, 0.f);
            if (MODE == 2) {
                // row = t*B+b, col = h*64+d  ->  qkv[((b*8+h)*512 + t)*64 + d]
                int t = row >> 5, b = row & 31;
                int h = col >> 6, d = col & 63;
                C[(((size_t)(b * 8 + h)) << 15) + ((size_t)t << 6) + d] = v;
            } else {
                C[(size_t)row * ldc + col] = v;
            }
        }
    }
}

// ---------------------------------------------------------------------------
// Flash-style attention. grid = (B*NH, T/32), 256 threads.
// qkv layout: [bh][t][d].  Output attnc[(t*B+b)*H + h*64 + d].
// ---------------------------------------------------------------------------
#define QT 32
#define KT 64
__global__ __launch_bounds__(256) void attn_kernel(
    const float* __restrict__ qb, const float* __restrict__ kb,
    const float* __restrict__ vb, const float* __restrict__ mask,
    const float* __restrict__ gammas, float* __restrict__ attnc)
{
    __shared__ __align__(16) float qs[QT][68];
    __shared__ __align__(16) float ks[KT][68];
    __shared__ __align__(16) float vs[KT][68];
    __shared__ float ps[QT][68];
    __shared__ float ms[QT], ls[QT];
    __shared__ float kmask[KT];

    const int bh = blockIdx.x;           // b*NH + h
    const int b  = bh >> 3;
    const int h  = bh & 7;
    const int qt0 = blockIdx.y * QT;
    const int tid = threadIdx.x;
    const int r  = tid >> 3;             // query row 0..31
    const int c1 = tid & 7;              // key sub-lane 0..7

    // stage Q tile (32 x 64)
    {
        int rr = tid >> 3, cc = (tid & 7) * 8;
        const float* qp = qb + ((size_t)bh * T_LEN + qt0 + rr) * DHEAD + cc;
        float4 a = *(const float4*)qp;
        float4 c = *(const float4*)(qp + 4);
        float* dst = &qs[rr][cc];
        dst[0]=a.x; dst[1]=a.y; dst[2]=a.z; dst[3]=a.w;
        dst[4]=c.x; dst[5]=c.y; dst[6]=c.z; dst[7]=c.w;
    }
    if (tid < QT) { ms[tid] = -3.0e38f; ls[tid] = 0.f; }

    float g  = gammas[h];
    float sp = (g > 20.f) ? g : log1pf(expf(g));   // softplus
    float o[8] = {0.f,0.f,0.f,0.f,0.f,0.f,0.f,0.f};
    const int qglob = qt0 + r;

    for (int kt0 = 0; kt0 < qt0 + QT; kt0 += KT) {
        // stage K,V tiles (64 x 64 each)
        {
            int rr = tid >> 2, cc = (tid & 3) * 16;
            const float* kp = kb + ((size_t)bh * T_LEN + kt0 + rr) * DHEAD + cc;
            const float* vp = vb + ((size_t)bh * T_LEN + kt0 + rr) * DHEAD + cc;
#pragma unroll
            for (int u = 0; u < 4; u++) {
                float4 kv = *(const float4*)(kp + 4 * u);
                float4 vv = *(const float4*)(vp + 4 * u);
                float* kd = &ks[rr][cc + 4 * u];
                float* vd = &vs[rr][cc + 4 * u];
                kd[0]=kv.x; kd[1]=kv.y; kd[2]=kv.z; kd[3]=kv.w;
                vd[0]=vv.x; vd[1]=vv.y; vd[2]=vv.z; vd[3]=vv.w;
            }
        }
        if (tid < KT) kmask[tid] = mask[(size_t)(kt0 + tid) * B_SZ + b];
        __syncthreads();

        // scores for row r, keys j = c1 + 8*jj
        float s[8];
#pragma unroll
        for (int jj = 0; jj < 8; jj++) s[jj] = 0.f;
        for (int d = 0; d < 64; d++) {
            float qv = qs[r][d];
#pragma unroll
            for (int jj = 0; jj < 8; jj++)
                s[jj] = fmaf(qv, ks[c1 + 8 * jj][d], s[jj]);
        }
#pragma unroll
        for (int jj = 0; jj < 8; jj++) {
            int j  = c1 + 8 * jj;
            int kg = kt0 + j;
            float sc = s[jj] * 0.125f;                 // 1/sqrt(64)
            if (kmask[j] == 0.f) sc = -1e32f;          // key padding mask
            float pe  = sqrtf(fabsf((float)(qglob - kg)));
            float eff = expf(-sp * pe);
            eff = fminf(fmaxf(eff, 1e-5f), 1e5f);
            sc *= eff;                                  // distance decay
            if (kg >= qglob) sc = -1e32f;               // causal (incl. diag)
            s[jj] = sc;
        }
        // online softmax (8 threads per row, same wave)
        float tmax = s[0];
#pragma unroll
        for (int jj = 1; jj < 8; jj++) tmax = fmaxf(tmax, s[jj]);
        tmax = fmaxf(tmax, __shfl_xor(tmax, 1, 64));
        tmax = fmaxf(tmax, __shfl_xor(tmax, 2, 64));
        tmax = fmaxf(tmax, __shfl_xor(tmax, 4, 64));
        float mold = ms[r];
        float mnew = fmaxf(mold, tmax);
        float alpha = expf(mold - mnew);
        float tsum = 0.f;
#pragma unroll
        for (int jj = 0; jj < 8; jj++) {
            float p = expf(s[jj] - mnew);
            ps[r][c1 + 8 * jj] = p;
            tsum += p;
        }
        tsum += __shfl_xor(tsum, 1, 64);
        tsum += __shfl_xor(tsum, 2, 64);
        tsum += __shfl_xor(tsum, 4, 64);
#pragma unroll
        for (int i = 0; i < 8; i++) o[i] *= alpha;
        if (c1 == 0) { ms[r] = mnew; ls[r] = ls[r] * alpha + tsum; }
        __syncthreads();
        // PV: o[di] covers dim dd = c1 + 8*di
        for (int j = 0; j < 64; j++) {
            float pv = ps[r][j];
#pragma unroll
            for (int di = 0; di < 8; di++)
                o[di] = fmaf(pv, vs[j][c1 + 8 * di], o[di]);
        }
        __syncthreads();
    }

    float linv = (qglob == 0) ? 0.f : 1.f / ls[r];   // row 0 zeroed by reference
#pragma unroll
    for (int di = 0; di < 8; di++) {
        int dd = c1 + 8 * di;
        attnc[((size_t)qglob * B_SZ + b) * H_DIM + h * DHEAD + dd] = o[di] * linv;
    }
}

// ---------------------------------------------------------------------------
// LayerNorm over 512, one wave per row. ADD: Y = res + LN(X) (row stride ldy)
// ---------------------------------------------------------------------------
template<bool ADD>
__global__ __launch_bounds__(256) void ln_kernel(
    const float* __restrict__ X, const float* __restrict__ g,
    const float* __restrict__ bta, const float* __restrict__ res,
    float* __restrict__ Y, int ldy)
{
    int m    = blockIdx.x * 4 + (threadIdx.x >> 6);
    int lane = threadIdx.x & 63;
    const float* xr = X + (size_t)m * H_DIM;
    float x[8];
    float s = 0.f, ss = 0.f;
#pragma unroll
    for (int i = 0; i < 8; i++) {
        x[i] = xr[lane + 64 * i];
        s += x[i]; ss += x[i] * x[i];
    }
#pragma unroll
    for (int off = 32; off >= 1; off >>= 1) {
        s  += __shfl_xor(s,  off, 64);
        ss += __shfl_xor(ss, off, 64);
    }
    float mu  = s * (1.f / 512.f);
    float var = ss * (1.f / 512.f) - mu * mu;
    float rs  = rsqrtf(var + 1e-5f);
    float* yr = Y + (size_t)m * ldy;
    const float* rr = res + (size_t)m * H_DIM;
#pragma unroll
    for (int i = 0; i < 8; i++) {
        int c = lane + 64 * i;
        float v = (x[i] - mu) * rs * g[c] + bta[c];
        if (ADD) v += rr[c];
        yr[c] = v;
    }
}

// ---------------------------------------------------------------------------
// predot: lg[row] = dot(pred[row,:], OW) + Ob  (one wave per row)
// ---------------------------------------------------------------------------
__global__ __launch_bounds__(256) void predot_kernel(
    const float* __restrict__ pred, const float* __restrict__ OW,
    const float* __restrict__ Ob, float* __restrict__ lg)
{
    int m    = blockIdx.x * 4 + (threadIdx.x >> 6);
    int lane = threadIdx.x & 63;
    const float* pr = pred + (size_t)m * P_DIM;
    float s = 0.f;
#pragma unroll 6
    for (int c = lane; c < P_DIM; c += 64)
        s = fmaf(pr[c], OW[c], s);
#pragma unroll
    for (int off = 32; off >= 1; off >>= 1) s += __shfl_xor(s, off, 64);
    if (lane == 0) lg[m] = s + Ob[0];
}

// ---------------------------------------------------------------------------
// BCE over logits; accumulate sum(bce*mask), sum(mask)
// ---------------------------------------------------------------------------
__global__ __launch_bounds__(256) void bce_kernel(
    const float* __restrict__ lg, const int* __restrict__ labels,
    const float* __restrict__ mask, float* __restrict__ accum)
{
    int m    = blockIdx.x * 256 + threadIdx.x;
    int lane = threadIdx.x & 63;
    float l  = lg[m];
    float y  = (float)labels[m];
    float mv = mask[m];
    float a  = (fmaxf(l, 0.f) - l * y + log1pf(expf(-fabsf(l)))) * mv;
#pragma unroll
    for (int off = 32; off >= 1; off >>= 1) {
        a  += __shfl_xor(a,  off, 64);
        mv += __shfl_xor(mv, off, 64);
    }
    if (lane == 0) {
        atomicAdd(accum,     a);
        atomicAdd(accum + 1, mv);
    }
}

__global__ void zero_accum(float* accum) { accum[0] = 0.f; accum[1] = 0.f; }

__global__ void finalize_kernel(const float* __restrict__ accum, float* __restrict__ out)
{
    out[0] = accum[0] / accum[1];
}

// ---------------------------------------------------------------------------
extern "C" void kernel_launch(void* const* d_in, const int* in_sizes, int n_in,
                              void* d_out, int out_size, void* d_ws, size_t ws_size,
                              hipStream_t stream)
{
    (void)in_sizes; (void)n_in; (void)out_size;
    const int*   ans    = (const int*)  d_in[0];
    const int*   cans   = (const int*)  d_in[1];
    const int*   labels = (const int*)  d_in[2];
    const float* mask   = (const float*)d_in[3];
    const int*   qids   = (const int*)  d_in[4];
    const int*   sids   = (const int*)  d_in[5];
    const float* smask  = (const float*)d_in[6];
    const float* Eq     = (const float*)d_in[7];
    const float* Es     = (const float*)d_in[8];
    const float* Ea     = (const float*)d_in[9];
    const float* El     = (const float*)d_in[10];
    const float* Wq     = (const float*)d_in[11];
    const float* bq     = (const float*)d_in[12];
    const float* Wk     = (const float*)d_in[13];
    const float* bk     = (const float*)d_in[14];
    const float* Wv     = (const float*)d_in[15];
    const float* bv     = (const float*)d_in[16];
    const float* Wo     = (const float*)d_in[17];
    const float* bo     = (const float*)d_in[18];
    const float* ln1_g  = (const float*)d_in[19];
    const float* ln1_b  = (const float*)d_in[20];
    const float* W1     = (const float*)d_in[21];
    const float* b1     = (const float*)d_in[22];
    const float* W2     = (const float*)d_in[23];
    const float* b2     = (const float*)d_in[24];
    const float* ln2_g  = (const float*)d_in[25];
    const float* ln2_b  = (const float*)d_in[26];
    const float* gammas = (const float*)d_in[27];
    const float* L1W    = (const float*)d_in[28];
    const float* L1b    = (const float*)d_in[29];
    const float* L2W    = (const float*)d_in[30];
    const float* L2b    = (const float*)d_in[31];
    const float* OW     = (const float*)d_in[32];
    const float* Ob     = (const float*)d_in[33];
    float* out = (float*)d_out;

    // Arena: units of U = 64*TB floats. Total 50U = 209,715,200 bytes.
    const size_t U = (size_t)TBTOK * 64;
    if (ws_size < 50 * U * sizeof(float)) return;   // refuse to overflow ws
    float* ws    = (float*)d_ws;
    float* pred  = ws;                 // [0,18)   permanent, TB x 1152
    float* slotB = ws + 18 * U;        // [18,26)
    float* slotC = ws + 26 * U;        // [26,34)
    float* slotD = ws + 34 * U;        // [34,42)
    float* slotE = ws + 42 * U;        // [42,50)

    float* labans = slotB;             // steps 1-2   (TB x 512)
    float* qb     = slotC;             // steps 2-3   [B*NH][T][64]
    float* kb     = slotD;
    float* vb     = slotE;
    float* attnc  = slotB;             // steps 3-4   (TB x 512)
    float* x1     = slotC;             // steps 4-5
    float* out1   = slotD;             // steps 5-8
    float* f1     = slotB;             // steps 6-7
    float* f2     = slotC;             // steps 7-8
    float* h1     = slotB;             // steps 9-10  (TB x 1152, spans [18,36))
    float* lgits  = slotE;             // steps 9-12  (TB floats)
    float* accum  = slotE + TBTOK;     // 2 floats

    // 1. embeddings
    embed_kernel<<<TBTOK, 256, 0, stream>>>(ans, cans, labels, mask, qids, sids,
                                            smask, Eq, Es, Ea, El, pred, labans);
    // 2. q,k,v projections
    gemm_nt<2,false><<<dim3(TBTOK/64, H_DIM/64), 256, 0, stream>>>(
        pred + 512, P_DIM, nullptr, Wq, DKEY, bq, qb, 0, DKEY, nullptr, nullptr);
    gemm_nt<2,false><<<dim3(TBTOK/64, H_DIM/64), 256, 0, stream>>>(
        pred + 512, P_DIM, nullptr, Wk, DKEY, bk, kb, 0, DKEY, nullptr, nullptr);
    gemm_nt<2,true><<<dim3(TBTOK/64, H_DIM/64), 256, 0, stream>>>(
        labans, 512, pred, Wv, DVAL, bv, vb, 0, DVAL, nullptr, nullptr);
    // 3. attention
    attn_kernel<<<dim3(B_SZ * NHEAD, T_LEN / QT), 256, 0, stream>>>(
        qb, kb, vb, mask, gammas, attnc);
    // 4. output projection
    gemm_nt<0,false><<<dim3(TBTOK/64, H_DIM/64), 256, 0, stream>>>(
        attnc, H_DIM, nullptr, Wo, H_DIM, bo, x1, H_DIM, H_DIM, nullptr, nullptr);
    // 5. LN1
    ln_kernel<false><<<TBTOK/4, 256, 0, stream>>>(x1, ln1_g, ln1_b, x1, out1, H_DIM);
    // 6-7. FFN
    gemm_nt<1,false><<<dim3(TBTOK/64, H_DIM/64), 256, 0, stream>>>(
        out1, H_DIM, nullptr, W1, H_DIM, b1, f1, H_DIM, H_DIM, nullptr, nullptr);
    gemm_nt<0,false><<<dim3(TBTOK/64, H_DIM/64), 256, 0, stream>>>(
        f1, H_DIM, nullptr, W2, H_DIM, b2, f2, H_DIM, H_DIM, nullptr, nullptr);
    // 8. pred[:, :512] = out1 + LN2(ffn)
    ln_kernel<true><<<TBTOK/4, 256, 0, stream>>>(f2, ln2_g, ln2_b, out1, pred, P_DIM);
    // 9. logits init = dot(pred, OW) + Ob   (qkv dead -> slotE free)
    zero_accum<<<1, 1, 0, stream>>>(accum);
    predot_kernel<<<TBTOK/4, 256, 0, stream>>>(pred, OW, Ob, lgits);
    // 10. L1 (relu)
    gemm_nt<1,false><<<dim3(TBTOK/64, P_DIM/64), 256, 0, stream>>>(
        pred, P_DIM, nullptr, L1W, P_DIM, L1b, h1, P_DIM, P_DIM, nullptr, nullptr);
    // 11. L2 (relu) fused with OW dot -> atomic into lgits
    gemm_nt<3,false><<<dim3(TBTOK/64, P_DIM/64), 256, 0, stream>>>(
        h1, P_DIM, nullptr, L2W, P_DIM, L2b, nullptr, 0, P_DIM, OW, lgits);
    // 12. BCE + reduction
    bce_kernel<<<TBTOK/256, 256, 0, stream>>>(lgits, labels, mask, accum);
    finalize_kernel<<<1, 1, 0, stream>>>(accum, out);
}

// Round 3
// 790.763 us; speedup vs baseline: 3.2222x; 3.2222x over previous
//
#include <hip/hip_runtime.h>
#include <math.h>

// Problem constants
#define T_LEN 512
#define B_SZ  32
#define NHEAD 8
#define DHEAD 64
#define H_DIM 512
#define TBTOK 16384          // T*B
#define P_DIM 1152

typedef unsigned short ushort_t;
typedef short short8 __attribute__((ext_vector_type(8)));
typedef float f32x4 __attribute__((ext_vector_type(4)));

__device__ __forceinline__ ushort_t f2bf(float f) {
    union { float f; unsigned int u; } v; v.f = f;
    unsigned int r = v.u + 0x7fffu + ((v.u >> 16) & 1u);
    return (ushort_t)(r >> 16);
}
__device__ __forceinline__ float bf2f(ushort_t h) {
    union { unsigned int u; float f; } v; v.u = ((unsigned int)h) << 16;
    return v.f;
}
__device__ __forceinline__ void gload_lds16(const void* g, void* l) {
    __builtin_amdgcn_global_load_lds(
        (const __attribute__((address_space(1))) void*)g,
        (__attribute__((address_space(3))) void*)l, 16, 0, 0);
}

// ---------------------------------------------------------------------------
// Weight fp32 -> bf16 packing (all 8 matrices into one arena)
// ---------------------------------------------------------------------------
__global__ __launch_bounds__(256) void convert_weights(
    const float* __restrict__ wq, const float* __restrict__ wk,
    const float* __restrict__ wv, const float* __restrict__ wo,
    const float* __restrict__ w1, const float* __restrict__ w2,
    const float* __restrict__ l1, const float* __restrict__ l2,
    ushort_t* __restrict__ dst)
{
    const unsigned int offs[9] = {0u, 327680u, 655360u, 1245184u, 1507328u,
                                  1769472u, 2031616u, 3358720u, 4685824u};
    unsigned int c = (blockIdx.x * 256 + threadIdx.x) * 4;   // element offset
    const float* srcs[8] = {wq, wk, wv, wo, w1, w2, l1, l2};
    int s = 0;
#pragma unroll
    for (int i = 0; i < 7; i++) s += (c >= offs[i + 1]) ? 1 : 0;
    float4 v = *(const float4*)(srcs[s] + (c - offs[s]));
    ushort4 o;
    o.x = f2bf(v.x); o.y = f2bf(v.y); o.z = f2bf(v.z); o.w = f2bf(v.w);
    *(ushort4*)(dst + c) = o;
}

// ---------------------------------------------------------------------------
// Embedding / gather (bf16 outputs):
//   pred_bf[:,512:1152] = [questions(128)|subjects(256)|ca(256)]
//   value_bf[:,0:1152]  = [lab|ans|ca|questions|subjects]
// ---------------------------------------------------------------------------
__global__ __launch_bounds__(256) void embed_kernel(
    const int* __restrict__ ans, const int* __restrict__ cans,
    const int* __restrict__ labels, const float* __restrict__ mask,
    const int* __restrict__ qids, const int* __restrict__ sids,
    const float* __restrict__ smask,
    const float* __restrict__ Eq, const float* __restrict__ Es,
    const float* __restrict__ Ea, const float* __restrict__ El,
    ushort_t* __restrict__ pred_bf, ushort_t* __restrict__ value_bf)
{
    int m = blockIdx.x;              // token = t*B + b
    int tid = threadIdx.x;           // 256
    float mval = mask[m];
    int qid = qids[m];
    int a   = ans[m] - 1;
    int ca  = cans[m] - 1;
    int lb  = labels[m];
    ushort_t* pr = pred_bf  + (size_t)m * P_DIM;
    ushort_t* vr = value_bf + (size_t)m * P_DIM;

    if (tid < 128) {
        ushort_t qv = f2bf(Eq[(size_t)qid * 128 + tid]);
        pr[512 + tid] = qv;
        vr[768 + tid] = qv;
    }
    int d = tid;                     // 0..255
    float s = 0.f;
#pragma unroll
    for (int j = 0; j < 8; j++) {
        int  sid = sids[m * 8 + j];
        float sm = smask[m * 8 + j];
        s += Es[(size_t)sid * 256 + d] * sm;
    }
    ushort_t sb = f2bf(s);
    pr[640 + d] = sb;
    vr[896 + d] = sb;
    ushort_t cab = f2bf(Ea[ca * 256 + d]);
    pr[896 + d] = cab;
    vr[512 + d] = cab;
    vr[256 + d] = f2bf(Ea[a * 256 + d] * mval);
    vr[0   + d] = f2bf(El[lb * 256 + d] * mval);
}

// ---------------------------------------------------------------------------
// MFMA bf16 GEMM: C(M x N) = A(M x K bf16) @ W(N x K bf16)^T + bias
// 128x128 tile, 256 thr (4 waves, 2x2 of 64x64), BK=32, 16x16x32 MFMA,
// global_load_lds width-16 staging (m97 structure).
// MODE 0: fp32 store  MODE 1: relu -> bf16 store  MODE 2: fp32 qkv scatter
// MODE 3: relu, dot with OW, atomicAdd into lg[row]
// ---------------------------------------------------------------------------
template<int MODE>
__global__ __launch_bounds__(256) void mgemm(
    const ushort_t* __restrict__ A, int lda,
    const ushort_t* __restrict__ W, int ldw,
    const float* __restrict__ bias,
    float* __restrict__ C, ushort_t* __restrict__ Cb, int ldc, int K,
    const float* __restrict__ OW, float* __restrict__ lg)
{
    __shared__ __align__(16) ushort_t As[128 * 32];
    __shared__ __align__(16) ushort_t Ws[128 * 32];

    const int m0 = blockIdx.x * 128;
    const int n0 = blockIdx.y * 128;
    const int tid  = threadIdx.x;
    const int wave = tid >> 6;
    const int lane = tid & 63;
    const int wm = wave & 1, wn = wave >> 1;

    f32x4 acc[4][4] = {};

    // staging: wave handles rows [wave*32, wave*32+32) as two 16-row groups;
    // lane -> row = grp*16 + (lane>>2), 16B chunk = (lane&3)*8 bf16
    const int srow   = lane >> 2;
    const int schunk = (lane & 3) * 8;
    const ushort_t* Ag0 = A + (size_t)(m0 + wave * 32 + srow) * lda + schunk;
    const ushort_t* Ag1 = Ag0 + (size_t)16 * lda;
    const ushort_t* Wg0 = W + (size_t)(n0 + wave * 32 + srow) * ldw + schunk;
    const ushort_t* Wg1 = Wg0 + (size_t)16 * ldw;
    ushort_t* Al0 = &As[(wave * 32) * 32];
    ushort_t* Al1 = &As[(wave * 32 + 16) * 32];
    ushort_t* Wl0 = &Ws[(wave * 32) * 32];
    ushort_t* Wl1 = &Ws[(wave * 32 + 16) * 32];

    const int fr   = lane & 15;      // fragment row(A)/col(B)
    const int quad = lane >> 4;

    for (int k0 = 0; k0 < K; k0 += 32) {
        gload_lds16(Ag0 + k0, Al0);
        gload_lds16(Ag1 + k0, Al1);
        gload_lds16(Wg0 + k0, Wl0);
        gload_lds16(Wg1 + k0, Wl1);
        __syncthreads();
        short8 af[4], wf[4];
#pragma unroll
        for (int i = 0; i < 4; i++)
            af[i] = *(const short8*)&As[(wm * 64 + i * 16 + fr) * 32 + quad * 8];
#pragma unroll
        for (int j = 0; j < 4; j++)
            wf[j] = *(const short8*)&Ws[(wn * 64 + j * 16 + fr) * 32 + quad * 8];
#pragma unroll
        for (int i = 0; i < 4; i++)
#pragma unroll
            for (int j = 0; j < 4; j++)
                acc[i][j] = __builtin_amdgcn_mfma_f32_16x16x32_bf16(
                    af[i], wf[j], acc[i][j], 0, 0, 0);
        __syncthreads();
    }

    // Epilogue. C/D layout: col = lane&15, row = quad*4 + reg (per 16x16 frag)
    if (MODE == 3) {
#pragma unroll
        for (int i = 0; i < 4; i++)
#pragma unroll
            for (int r = 0; r < 4; r++) {
                int row = m0 + wm * 64 + i * 16 + quad * 4 + r;
                float part = 0.f;
#pragma unroll
                for (int j = 0; j < 4; j++) {
                    int col = n0 + wn * 64 + j * 16 + fr;
                    float v = fmaxf(acc[i][j][r] + bias[col], 0.f);
                    part = fmaf(v, OW[col], part);
                }
                part += __shfl_xor(part, 1, 64);
                part += __shfl_xor(part, 2, 64);
                part += __shfl_xor(part, 4, 64);
                part += __shfl_xor(part, 8, 64);
                if (fr == 0) atomicAdd(&lg[row], part);
            }
        return;
    }

#pragma unroll
    for (int i = 0; i < 4; i++)
#pragma unroll
        for (int r = 0; r < 4; r++) {
            int row = m0 + wm * 64 + i * 16 + quad * 4 + r;
#pragma unroll
            for (int j = 0; j < 4; j++) {
                int col = n0 + wn * 64 + j * 16 + fr;
                float v = acc[i][j][r] + bias[col];
                if (MODE == 0) {
                    C[(size_t)row * ldc + col] = v;
                } else if (MODE == 1) {
                    Cb[(size_t)row * ldc + col] = f2bf(fmaxf(v, 0.f));
                } else { // MODE 2: row=t*B+b, col=h*64+d -> [b*8+h][t][d]
                    int t = row >> 5, b = row & 31;
                    int h = col >> 6, d = col & 63;
                    C[(((size_t)(b * 8 + h)) << 15) + ((size_t)t << 6) + d] = v;
                }
            }
        }
}

// ---------------------------------------------------------------------------
// Flash-style attention (fp32). grid = (B*NH, T/32), 256 threads.
// qkv layout: [bh][t][d].  Output bf16 attnc[(t*B+b)*H + h*64 + d].
// ---------------------------------------------------------------------------
#define QT 32
#define KT 64
__global__ __launch_bounds__(256) void attn_kernel(
    const float* __restrict__ qb, const float* __restrict__ kb,
    const float* __restrict__ vb, const float* __restrict__ mask,
    const float* __restrict__ gammas, ushort_t* __restrict__ attnc)
{
    __shared__ __align__(16) float qs[QT][68];
    __shared__ __align__(16) float ks[KT][68];
    __shared__ __align__(16) float vs[KT][68];
    __shared__ float ps[QT][68];
    __shared__ float ms[QT], ls[QT];
    __shared__ float kmask[KT];

    const int bh = blockIdx.x;           // b*NH + h
    const int b  = bh >> 3;
    const int h  = bh & 7;
    const int qt0 = blockIdx.y * QT;
    const int tid = threadIdx.x;
    const int r  = tid >> 3;             // query row 0..31
    const int c1 = tid & 7;              // key sub-lane 0..7

    {
        int rr = tid >> 3, cc = (tid & 7) * 8;
        const float* qp = qb + ((size_t)bh * T_LEN + qt0 + rr) * DHEAD + cc;
        float4 a = *(const float4*)qp;
        float4 c = *(const float4*)(qp + 4);
        float* dst = &qs[rr][cc];
        dst[0]=a.x; dst[1]=a.y; dst[2]=a.z; dst[3]=a.w;
        dst[4]=c.x; dst[5]=c.y; dst[6]=c.z; dst[7]=c.w;
    }
    if (tid < QT) { ms[tid] = -3.0e38f; ls[tid] = 0.f; }

    float g  = gammas[h];
    float sp = (g > 20.f) ? g : log1pf(expf(g));   // softplus
    float o[8] = {0.f,0.f,0.f,0.f,0.f,0.f,0.f,0.f};
    const int qglob = qt0 + r;

    for (int kt0 = 0; kt0 < qt0 + QT; kt0 += KT) {
        {
            int rr = tid >> 2, cc = (tid & 3) * 16;
            const float* kp = kb + ((size_t)bh * T_LEN + kt0 + rr) * DHEAD + cc;
            const float* vp = vb + ((size_t)bh * T_LEN + kt0 + rr) * DHEAD + cc;
#pragma unroll
            for (int u = 0; u < 4; u++) {
                float4 kv = *(const float4*)(kp + 4 * u);
                float4 vv = *(const float4*)(vp + 4 * u);
                float* kd = &ks[rr][cc + 4 * u];
                float* vd = &vs[rr][cc + 4 * u];
                kd[0]=kv.x; kd[1]=kv.y; kd[2]=kv.z; kd[3]=kv.w;
                vd[0]=vv.x; vd[1]=vv.y; vd[2]=vv.z; vd[3]=vv.w;
            }
        }
        if (tid < KT) kmask[tid] = mask[(size_t)(kt0 + tid) * B_SZ + b];
        __syncthreads();

        float s[8];
#pragma unroll
        for (int jj = 0; jj < 8; jj++) s[jj] = 0.f;
        for (int d = 0; d < 64; d++) {
            float qv = qs[r][d];
#pragma unroll
            for (int jj = 0; jj < 8; jj++)
                s[jj] = fmaf(qv, ks[c1 + 8 * jj][d], s[jj]);
        }
#pragma unroll
        for (int jj = 0; jj < 8; jj++) {
            int j  = c1 + 8 * jj;
            int kg = kt0 + j;
            float sc = s[jj] * 0.125f;                 // 1/sqrt(64)
            if (kmask[j] == 0.f) sc = -1e32f;
            float pe  = sqrtf(fabsf((float)(qglob - kg)));
            float eff = expf(-sp * pe);
            eff = fminf(fmaxf(eff, 1e-5f), 1e5f);
            sc *= eff;
            if (kg >= qglob) sc = -1e32f;              // causal (incl. diag)
            s[jj] = sc;
        }
        float tmax = s[0];
#pragma unroll
        for (int jj = 1; jj < 8; jj++) tmax = fmaxf(tmax, s[jj]);
        tmax = fmaxf(tmax, __shfl_xor(tmax, 1, 64));
        tmax = fmaxf(tmax, __shfl_xor(tmax, 2, 64));
        tmax = fmaxf(tmax, __shfl_xor(tmax, 4, 64));
        float mold = ms[r];
        float mnew = fmaxf(mold, tmax);
        float alpha = expf(mold - mnew);
        float tsum = 0.f;
#pragma unroll
        for (int jj = 0; jj < 8; jj++) {
            float p = expf(s[jj] - mnew);
            ps[r][c1 + 8 * jj] = p;
            tsum += p;
        }
        tsum += __shfl_xor(tsum, 1, 64);
        tsum += __shfl_xor(tsum, 2, 64);
        tsum += __shfl_xor(tsum, 4, 64);
#pragma unroll
        for (int i = 0; i < 8; i++) o[i] *= alpha;
        if (c1 == 0) { ms[r] = mnew; ls[r] = ls[r] * alpha + tsum; }
        __syncthreads();
        for (int j = 0; j < 64; j++) {
            float pv = ps[r][j];
#pragma unroll
            for (int di = 0; di < 8; di++)
                o[di] = fmaf(pv, vs[j][c1 + 8 * di], o[di]);
        }
        __syncthreads();
    }

    float linv = (qglob == 0) ? 0.f : 1.f / ls[r];
#pragma unroll
    for (int di = 0; di < 8; di++) {
        int dd = c1 + 8 * di;
        attnc[((size_t)qglob * B_SZ + b) * H_DIM + h * DHEAD + dd] =
            f2bf(o[di] * linv);
    }
}

// ---------------------------------------------------------------------------
// LN1: out1 = LN(x1);  writes fp32 + bf16
// ---------------------------------------------------------------------------
__global__ __launch_bounds__(256) void ln1_kernel(
    const float* __restrict__ X, const float* __restrict__ g,
    const float* __restrict__ bta, float* __restrict__ Y,
    ushort_t* __restrict__ Yb)
{
    int m    = blockIdx.x * 4 + (threadIdx.x >> 6);
    int lane = threadIdx.x & 63;
    const float* xr = X + (size_t)m * H_DIM;
    float x[8];
    float s = 0.f, ss = 0.f;
#pragma unroll
    for (int i = 0; i < 8; i++) {
        x[i] = xr[lane + 64 * i];
        s += x[i]; ss += x[i] * x[i];
    }
#pragma unroll
    for (int off = 32; off >= 1; off >>= 1) {
        s  += __shfl_xor(s,  off, 64);
        ss += __shfl_xor(ss, off, 64);
    }
    float mu  = s * (1.f / 512.f);
    float var = ss * (1.f / 512.f) - mu * mu;
    float rs  = rsqrtf(var + 1e-5f);
#pragma unroll
    for (int i = 0; i < 8; i++) {
        int c = lane + 64 * i;
        float v = (x[i] - mu) * rs * g[c] + bta[c];
        Y[(size_t)m * H_DIM + c]  = v;
        Yb[(size_t)m * H_DIM + c] = f2bf(v);
    }
}

// ---------------------------------------------------------------------------
// LN2 + residual: pred_bf[:, 0:512] = bf16(out1 + LN(f2))
// ---------------------------------------------------------------------------
__global__ __launch_bounds__(256) void ln2_kernel(
    const float* __restrict__ X, const float* __restrict__ g,
    const float* __restrict__ bta, const float* __restrict__ res,
    ushort_t* __restrict__ pred_bf)
{
    int m    = blockIdx.x * 4 + (threadIdx.x >> 6);
    int lane = threadIdx.x & 63;
    const float* xr = X + (size_t)m * H_DIM;
    float x[8];
    float s = 0.f, ss = 0.f;
#pragma unroll
    for (int i = 0; i < 8; i++) {
        x[i] = xr[lane + 64 * i];
        s += x[i]; ss += x[i] * x[i];
    }
#pragma unroll
    for (int off = 32; off >= 1; off >>= 1) {
        s  += __shfl_xor(s,  off, 64);
        ss += __shfl_xor(ss, off, 64);
    }
    float mu  = s * (1.f / 512.f);
    float var = ss * (1.f / 512.f) - mu * mu;
    float rs  = rsqrtf(var + 1e-5f);
    const float* rr = res + (size_t)m * H_DIM;
#pragma unroll
    for (int i = 0; i < 8; i++) {
        int c = lane + 64 * i;
        float v = (x[i] - mu) * rs * g[c] + bta[c] + rr[c];
        pred_bf[(size_t)m * P_DIM + c] = f2bf(v);
    }
}

// ---------------------------------------------------------------------------
// predot: lg[row] = dot(pred_bf[row,:], OW) + Ob  (one wave per row)
// ---------------------------------------------------------------------------
__global__ __launch_bounds__(256) void predot_kernel(
    const ushort_t* __restrict__ pred_bf, const float* __restrict__ OW,
    const float* __restrict__ Ob, float* __restrict__ lg)
{
    int m    = blockIdx.x * 4 + (threadIdx.x >> 6);
    int lane = threadIdx.x & 63;
    const ushort_t* pr = pred_bf + (size_t)m * P_DIM;
    float s = 0.f;
#pragma unroll 6
    for (int c = lane; c < P_DIM; c += 64)
        s = fmaf(bf2f(pr[c]), OW[c], s);
#pragma unroll
    for (int off = 32; off >= 1; off >>= 1) s += __shfl_xor(s, off, 64);
    if (lane == 0) lg[m] = s + Ob[0];
}

// ---------------------------------------------------------------------------
__global__ __launch_bounds__(256) void bce_kernel(
    const float* __restrict__ lg, const int* __restrict__ labels,
    const float* __restrict__ mask, float* __restrict__ accum)
{
    int m    = blockIdx.x * 256 + threadIdx.x;
    int lane = threadIdx.x & 63;
    float l  = lg[m];
    float y  = (float)labels[m];
    float mv = mask[m];
    float a  = (fmaxf(l, 0.f) - l * y + log1pf(expf(-fabsf(l)))) * mv;
#pragma unroll
    for (int off = 32; off >= 1; off >>= 1) {
        a  += __shfl_xor(a,  off, 64);
        mv += __shfl_xor(mv, off, 64);
    }
    if (lane == 0) {
        atomicAdd(accum,     a);
        atomicAdd(accum + 1, mv);
    }
}

__global__ void zero_accum(float* accum) { accum[0] = 0.f; accum[1] = 0.f; }

__global__ void finalize_kernel(const float* __restrict__ accum, float* __restrict__ out)
{
    out[0] = accum[0] / accum[1];
}

// ---------------------------------------------------------------------------
extern "C" void kernel_launch(void* const* d_in, const int* in_sizes, int n_in,
                              void* d_out, int out_size, void* d_ws, size_t ws_size,
                              hipStream_t stream)
{
    (void)in_sizes; (void)n_in; (void)out_size;
    const int*   ans    = (const int*)  d_in[0];
    const int*   cans   = (const int*)  d_in[1];
    const int*   labels = (const int*)  d_in[2];
    const float* mask   = (const float*)d_in[3];
    const int*   qids   = (const int*)  d_in[4];
    const int*   sids   = (const int*)  d_in[5];
    const float* smask  = (const float*)d_in[6];
    const float* Eq     = (const float*)d_in[7];
    const float* Es     = (const float*)d_in[8];
    const float* Ea     = (const float*)d_in[9];
    const float* El     = (const float*)d_in[10];
    const float* Wq     = (const float*)d_in[11];
    const float* bq     = (const float*)d_in[12];
    const float* Wk     = (const float*)d_in[13];
    const float* bk     = (const float*)d_in[14];
    const float* Wv     = (const float*)d_in[15];
    const float* bv     = (const float*)d_in[16];
    const float* Wo     = (const float*)d_in[17];
    const float* bo     = (const float*)d_in[18];
    const float* ln1_g  = (const float*)d_in[19];
    const float* ln1_b  = (const float*)d_in[20];
    const float* W1     = (const float*)d_in[21];
    const float* b1     = (const float*)d_in[22];
    const float* W2     = (const float*)d_in[23];
    const float* b2     = (const float*)d_in[24];
    const float* ln2_g  = (const float*)d_in[25];
    const float* ln2_b  = (const float*)d_in[26];
    const float* gammas = (const float*)d_in[27];
    const float* L1W    = (const float*)d_in[28];
    const float* L1b    = (const float*)d_in[29];
    const float* L2W    = (const float*)d_in[30];
    const float* L2b    = (const float*)d_in[31];
    const float* OW     = (const float*)d_in[32];
    const float* Ob     = (const float*)d_in[33];
    float* out = (float*)d_out;

    // Arena in units U = TB*64 floats (4 MiB). Total 50U = 209,715,200 B.
    const size_t U = (size_t)TBTOK * 64;
    if (ws_size < 50 * U * sizeof(float)) return;
    float* ws = (float*)d_ws;
    ushort_t* wtb      = (ushort_t*)(ws);            // [0,3)  weights bf16 (perm)
    ushort_t* pred_bf  = (ushort_t*)(ws + 3 * U);    // [3,12) perm
    ushort_t* value_bf = (ushort_t*)(ws + 12 * U);   // [12,21) until V-gemm
    float*    out1     = ws + 12 * U;                // [12,20) LN1..LN2
    float*    qb       = ws + 21 * U;                // [21,29) until attn
    float*    x1       = ws + 21 * U;                //   then Wo-out / LN1-in
    ushort_t* f1_bf    = (ushort_t*)(ws + 21 * U);   //   then W1-out [21,25)
    ushort_t* h1_bf    = (ushort_t*)(ws + 21 * U);   //   then L1-out [21,30)
    float*    kb       = ws + 29 * U;                // [29,37) until attn
    float*    f2       = ws + 29 * U;                //   then W2-out / LN2-in
    float*    vb       = ws + 37 * U;                // [37,45) until attn
    ushort_t* out1_bf  = (ushort_t*)(ws + 37 * U);   //   then [37,41)
    ushort_t* attnc_bf = (ushort_t*)(ws + 45 * U);   // [45,49)
    float*    lgits    = ws + 49 * U;                // [49,50)
    float*    accum    = lgits + TBTOK;

    // bf16 weight arena offsets (elements)
    ushort_t* wq_b = wtb + 0;
    ushort_t* wk_b = wtb + 327680;
    ushort_t* wv_b = wtb + 655360;
    ushort_t* wo_b = wtb + 1245184;
    ushort_t* w1_b = wtb + 1507328;
    ushort_t* w2_b = wtb + 1769472;
    ushort_t* l1_b = wtb + 2031616;
    ushort_t* l2_b = wtb + 3358720;

    convert_weights<<<4576, 256, 0, stream>>>(Wq, Wk, Wv, Wo, W1, W2, L1W, L2W, wtb);
    embed_kernel<<<TBTOK, 256, 0, stream>>>(ans, cans, labels, mask, qids, sids,
                                            smask, Eq, Es, Ea, El, pred_bf, value_bf);
    // q,k,v projections (MFMA, scatter epilogue)
    mgemm<2><<<dim3(TBTOK/128, 4), 256, 0, stream>>>(
        pred_bf + 512, P_DIM, wq_b, 640, bq, qb, nullptr, 0, 640, nullptr, nullptr);
    mgemm<2><<<dim3(TBTOK/128, 4), 256, 0, stream>>>(
        pred_bf + 512, P_DIM, wk_b, 640, bk, kb, nullptr, 0, 640, nullptr, nullptr);
    mgemm<2><<<dim3(TBTOK/128, 4), 256, 0, stream>>>(
        value_bf, P_DIM, wv_b, P_DIM, bv, vb, nullptr, 0, P_DIM, nullptr, nullptr);
    // attention
    attn_kernel<<<dim3(B_SZ * NHEAD, T_LEN / QT), 256, 0, stream>>>(
        qb, kb, vb, mask, gammas, attnc_bf);
    // output projection -> x1 (fp32)
    mgemm<0><<<dim3(TBTOK/128, 4), 256, 0, stream>>>(
        attnc_bf, H_DIM, wo_b, H_DIM, bo, x1, nullptr, H_DIM, H_DIM, nullptr, nullptr);
    ln1_kernel<<<TBTOK/4, 256, 0, stream>>>(x1, ln1_g, ln1_b, out1, out1_bf);
    // FFN
    mgemm<1><<<dim3(TBTOK/128, 4), 256, 0, stream>>>(
        out1_bf, H_DIM, w1_b, H_DIM, b1, nullptr, f1_bf, H_DIM, H_DIM, nullptr, nullptr);
    mgemm<0><<<dim3(TBTOK/128, 4), 256, 0, stream>>>(
        f1_bf, H_DIM, w2_b, H_DIM, b2, f2, nullptr, H_DIM, H_DIM, nullptr, nullptr);
    ln2_kernel<<<TBTOK/4, 256, 0, stream>>>(f2, ln2_g, ln2_b, out1, pred_bf);
    // logits init = dot(pred, OW) + Ob
    zero_accum<<<1, 1, 0, stream>>>(accum);
    predot_kernel<<<TBTOK/4, 256, 0, stream>>>(pred_bf, OW, Ob, lgits);
    // L1 (relu, bf16 out)
    mgemm<1><<<dim3(TBTOK/128, 9), 256, 0, stream>>>(
        pred_bf, P_DIM, l1_b, P_DIM, L1b, nullptr, h1_bf, P_DIM, P_DIM, nullptr, nullptr);
    // L2 (relu) fused with OW dot -> atomics into lgits
    mgemm<3><<<dim3(TBTOK/128, 9), 256, 0, stream>>>(
        h1_bf, P_DIM, l2_b, P_DIM, L2b, nullptr, nullptr, 0, P_DIM, OW, lgits);
    // BCE + reduction
    bce_kernel<<<TBTOK/256, 256, 0, stream>>>(lgits, labels, mask, accum);
    finalize_kernel<<<1, 1, 0, stream>>>(accum, out);
}

// Round 4
// 630.624 us; speedup vs baseline: 4.0404x; 1.2539x over previous
//
#include <hip/hip_runtime.h>
#include <math.h>

// Problem constants
#define T_LEN 512
#define B_SZ  32
#define NHEAD 8
#define DHEAD 64
#define H_DIM 512
#define TBTOK 16384          // T*B
#define P_DIM 1152

typedef unsigned short ushort_t;
typedef short short8 __attribute__((ext_vector_type(8)));
typedef float f32x4 __attribute__((ext_vector_type(4)));

__device__ __forceinline__ ushort_t f2bf(float f) {
    union { float f; unsigned int u; } v; v.f = f;
    unsigned int r = v.u + 0x7fffu + ((v.u >> 16) & 1u);
    return (ushort_t)(r >> 16);
}
__device__ __forceinline__ float bf2f(ushort_t h) {
    union { unsigned int u; float f; } v; v.u = ((unsigned int)h) << 16;
    return v.f;
}
__device__ __forceinline__ void gload_lds16(const void* g, void* l) {
    __builtin_amdgcn_global_load_lds(
        (const __attribute__((address_space(1))) void*)g,
        (__attribute__((address_space(3))) void*)l, 16, 0, 0);
}

// ---------------------------------------------------------------------------
// Weight fp32 -> bf16 packing (all 8 matrices into one arena)
// ---------------------------------------------------------------------------
__global__ __launch_bounds__(256) void convert_weights(
    const float* __restrict__ wq, const float* __restrict__ wk,
    const float* __restrict__ wv, const float* __restrict__ wo,
    const float* __restrict__ w1, const float* __restrict__ w2,
    const float* __restrict__ l1, const float* __restrict__ l2,
    ushort_t* __restrict__ dst)
{
    const unsigned int offs[9] = {0u, 327680u, 655360u, 1245184u, 1507328u,
                                  1769472u, 2031616u, 3358720u, 4685824u};
    unsigned int c = (blockIdx.x * 256 + threadIdx.x) * 4;   // element offset
    const float* srcs[8] = {wq, wk, wv, wo, w1, w2, l1, l2};
    int s = 0;
#pragma unroll
    for (int i = 0; i < 7; i++) s += (c >= offs[i + 1]) ? 1 : 0;
    float4 v = *(const float4*)(srcs[s] + (c - offs[s]));
    ushort4 o;
    o.x = f2bf(v.x); o.y = f2bf(v.y); o.z = f2bf(v.z); o.w = f2bf(v.w);
    *(ushort4*)(dst + c) = o;
}

// ---------------------------------------------------------------------------
// Embedding / gather (bf16 outputs):
//   pred_bf[:,512:1152] = [questions(128)|subjects(256)|ca(256)]
//   value_bf[:,0:1152]  = [lab|ans|ca|questions|subjects]
// ---------------------------------------------------------------------------
__global__ __launch_bounds__(256) void embed_kernel(
    const int* __restrict__ ans, const int* __restrict__ cans,
    const int* __restrict__ labels, const float* __restrict__ mask,
    const int* __restrict__ qids, const int* __restrict__ sids,
    const float* __restrict__ smask,
    const float* __restrict__ Eq, const float* __restrict__ Es,
    const float* __restrict__ Ea, const float* __restrict__ El,
    ushort_t* __restrict__ pred_bf, ushort_t* __restrict__ value_bf)
{
    int m = blockIdx.x;              // token = t*B + b
    int tid = threadIdx.x;           // 256
    float mval = mask[m];
    int qid = qids[m];
    int a   = ans[m] - 1;
    int ca  = cans[m] - 1;
    int lb  = labels[m];
    ushort_t* pr = pred_bf  + (size_t)m * P_DIM;
    ushort_t* vr = value_bf + (size_t)m * P_DIM;

    if (tid < 128) {
        ushort_t qv = f2bf(Eq[(size_t)qid * 128 + tid]);
        pr[512 + tid] = qv;
        vr[768 + tid] = qv;
    }
    int d = tid;                     // 0..255
    float s = 0.f;
#pragma unroll
    for (int j = 0; j < 8; j++) {
        int  sid = sids[m * 8 + j];
        float sm = smask[m * 8 + j];
        s += Es[(size_t)sid * 256 + d] * sm;
    }
    ushort_t sb = f2bf(s);
    pr[640 + d] = sb;
    vr[896 + d] = sb;
    ushort_t cab = f2bf(Ea[ca * 256 + d]);
    pr[896 + d] = cab;
    vr[512 + d] = cab;
    vr[256 + d] = f2bf(Ea[a * 256 + d] * mval);
    vr[0   + d] = f2bf(El[lb * 256 + d] * mval);
}

// ---------------------------------------------------------------------------
// MFMA bf16 GEMM: C(M x N) = A(M x K bf16) @ W(N x K bf16)^T + bias
// 128x128 tile, 256 thr (4 waves, 2x2 of 64x64), BK=32, 16x16x32 MFMA,
// global_load_lds width-16 staging (m97 structure).
// MODE 0: fp32 store            MODE 1: relu -> bf16 store
// MODE 2: bf16 qkv scatter [bh][t][d]
// MODE 3: relu, dot with OW, atomicAdd into lg[row]
// MODE 4: bf16 qkv scatter transposed [bh][d][t]  (for V)
// ---------------------------------------------------------------------------
template<int MODE>
__global__ __launch_bounds__(256) void mgemm(
    const ushort_t* __restrict__ A, int lda,
    const ushort_t* __restrict__ W, int ldw,
    const float* __restrict__ bias,
    float* __restrict__ C, ushort_t* __restrict__ Cb, int ldc, int K,
    const float* __restrict__ OW, float* __restrict__ lg)
{
    __shared__ __align__(16) ushort_t As[128 * 32];
    __shared__ __align__(16) ushort_t Ws[128 * 32];

    const int m0 = blockIdx.x * 128;
    const int n0 = blockIdx.y * 128;
    const int tid  = threadIdx.x;
    const int wave = tid >> 6;
    const int lane = tid & 63;
    const int wm = wave & 1, wn = wave >> 1;

    f32x4 acc[4][4] = {};

    const int srow   = lane >> 2;
    const int schunk = (lane & 3) * 8;
    const ushort_t* Ag0 = A + (size_t)(m0 + wave * 32 + srow) * lda + schunk;
    const ushort_t* Ag1 = Ag0 + (size_t)16 * lda;
    const ushort_t* Wg0 = W + (size_t)(n0 + wave * 32 + srow) * ldw + schunk;
    const ushort_t* Wg1 = Wg0 + (size_t)16 * ldw;
    ushort_t* Al0 = &As[(wave * 32) * 32];
    ushort_t* Al1 = &As[(wave * 32 + 16) * 32];
    ushort_t* Wl0 = &Ws[(wave * 32) * 32];
    ushort_t* Wl1 = &Ws[(wave * 32 + 16) * 32];

    const int fr   = lane & 15;      // fragment row(A)/col(B)
    const int quad = lane >> 4;

    for (int k0 = 0; k0 < K; k0 += 32) {
        gload_lds16(Ag0 + k0, Al0);
        gload_lds16(Ag1 + k0, Al1);
        gload_lds16(Wg0 + k0, Wl0);
        gload_lds16(Wg1 + k0, Wl1);
        __syncthreads();
        short8 af[4], wf[4];
#pragma unroll
        for (int i = 0; i < 4; i++)
            af[i] = *(const short8*)&As[(wm * 64 + i * 16 + fr) * 32 + quad * 8];
#pragma unroll
        for (int j = 0; j < 4; j++)
            wf[j] = *(const short8*)&Ws[(wn * 64 + j * 16 + fr) * 32 + quad * 8];
#pragma unroll
        for (int i = 0; i < 4; i++)
#pragma unroll
            for (int j = 0; j < 4; j++)
                acc[i][j] = __builtin_amdgcn_mfma_f32_16x16x32_bf16(
                    af[i], wf[j], acc[i][j], 0, 0, 0);
        __syncthreads();
    }

    // Epilogue. C/D layout: col = lane&15, row = quad*4 + reg (per 16x16 frag)
    if (MODE == 3) {
#pragma unroll
        for (int i = 0; i < 4; i++)
#pragma unroll
            for (int r = 0; r < 4; r++) {
                int row = m0 + wm * 64 + i * 16 + quad * 4 + r;
                float part = 0.f;
#pragma unroll
                for (int j = 0; j < 4; j++) {
                    int col = n0 + wn * 64 + j * 16 + fr;
                    float v = fmaxf(acc[i][j][r] + bias[col], 0.f);
                    part = fmaf(v, OW[col], part);
                }
                part += __shfl_xor(part, 1, 64);
                part += __shfl_xor(part, 2, 64);
                part += __shfl_xor(part, 4, 64);
                part += __shfl_xor(part, 8, 64);
                if (fr == 0) atomicAdd(&lg[row], part);
            }
        return;
    }

#pragma unroll
    for (int i = 0; i < 4; i++)
#pragma unroll
        for (int r = 0; r < 4; r++) {
            int row = m0 + wm * 64 + i * 16 + quad * 4 + r;
#pragma unroll
            for (int j = 0; j < 4; j++) {
                int col = n0 + wn * 64 + j * 16 + fr;
                float v = acc[i][j][r] + bias[col];
                if (MODE == 0) {
                    C[(size_t)row * ldc + col] = v;
                } else if (MODE == 1) {
                    Cb[(size_t)row * ldc + col] = f2bf(fmaxf(v, 0.f));
                } else if (MODE == 2) {
                    // row=t*B+b, col=h*64+d -> [b*8+h][t][d] bf16
                    int t = row >> 5, b = row & 31;
                    int h = col >> 6, d = col & 63;
                    Cb[(((size_t)(b * 8 + h)) << 15) + ((size_t)t << 6) + d] = f2bf(v);
                } else { // MODE 4: V transposed -> [b*8+h][d][t] bf16
                    int t = row >> 5, b = row & 31;
                    int h = col >> 6, d = col & 63;
                    Cb[(((size_t)(b * 8 + h)) << 15) + ((size_t)d << 9) + t] = f2bf(v);
                }
            }
        }
}

// ---------------------------------------------------------------------------
// MFMA flash attention. grid = (B*NH, 8 reversed q-tiles), 256 threads.
// qb,kb: bf16 [bh][t][64]; vtb: bf16 [bh][d][512].
// Output bf16 attnc[(t*B+b)*512 + h*64 + d].
// Each wave owns 16 q-rows; no barriers in the K-loop (P round-trip is
// wave-private LDS, K/V fragments read straight from global/L2).
// ---------------------------------------------------------------------------
__global__ __launch_bounds__(256) void attn_mfma(
    const ushort_t* __restrict__ qb, const ushort_t* __restrict__ kb,
    const ushort_t* __restrict__ vtb, const float* __restrict__ mask,
    const float* __restrict__ gammas, ushort_t* __restrict__ attnc)
{
    __shared__ __align__(16) ushort_t ps[4][16][72];   // P round-trip, per wave
    __shared__ float decay[512];
    __shared__ float mcol[512];

    const int bh  = blockIdx.x;          // b*8 + h
    const int b   = bh >> 3;
    const int h   = bh & 7;
    const int qt0 = (7 - blockIdx.y) * 64;   // heavy tiles first
    const int tid  = threadIdx.x;
    const int wave = tid >> 6;
    const int lane = tid & 63;
    const int fr   = lane & 15;
    const int quad = lane >> 4;

    {   // decay LUT + mask column for this (h, b)
        float g  = gammas[h];
        float sp = (g > 20.f) ? g : log1pf(expf(g));
        for (int i = tid; i < 512; i += 256) {
            decay[i] = fmaxf(expf(-sp * sqrtf((float)i)), 1e-5f);
            mcol[i]  = mask[(size_t)i * B_SZ + b];
        }
    }
    __syncthreads();

    const int qr0 = qt0 + wave * 16;
    const ushort_t* qbase = qb  + ((size_t)bh << 15);   // [t][64]
    const ushort_t* kbase = kb  + ((size_t)bh << 15);
    const ushort_t* vbase = vtb + ((size_t)bh << 15);   // [d][512]

    // Q fragments (A-operand): rows qr0+fr, d-chunks {0..31, 32..63}
    short8 af0 = *(const short8*)(qbase + (size_t)(qr0 + fr) * 64 + quad * 8);
    short8 af1 = *(const short8*)(qbase + (size_t)(qr0 + fr) * 64 + 32 + quad * 8);

    f32x4 o[4] = {};                       // O[q=quad*4+r][d=j2*16+fr]
    float mrow[4] = {-3e38f, -3e38f, -3e38f, -3e38f};
    float lrow[4] = {0.f, 0.f, 0.f, 0.f};

    for (int kt0 = 0; kt0 <= qt0; kt0 += 64) {
        // ---- S = Q K^T (16 x 64) ----
        f32x4 sacc[4] = {};
#pragma unroll
        for (int j = 0; j < 4; j++) {
            const ushort_t* kr = kbase + (size_t)(kt0 + j * 16 + fr) * 64;
            short8 k0 = *(const short8*)(kr + quad * 8);
            short8 k1 = *(const short8*)(kr + 32 + quad * 8);
            sacc[j] = __builtin_amdgcn_mfma_f32_16x16x32_bf16(af0, k0, sacc[j], 0, 0, 0);
            sacc[j] = __builtin_amdgcn_mfma_f32_16x16x32_bf16(af1, k1, sacc[j], 0, 0, 0);
        }
        // ---- mask / decay / causal;  element (q=qr0+quad*4+r, k=kt0+j*16+fr)
        float tmax[4] = {-3e38f, -3e38f, -3e38f, -3e38f};
#pragma unroll
        for (int j = 0; j < 4; j++) {
            int kg = kt0 + j * 16 + fr;
            float km = mcol[kg];
#pragma unroll
            for (int r = 0; r < 4; r++) {
                int qg = qr0 + quad * 4 + r;
                float sc = sacc[j][r] * 0.125f;
                if (km == 0.f) sc = -1e32f;
                int didx = qg - kg;
                float dec = decay[didx < 0 ? 0 : didx];
                sc = (kg < qg) ? sc * dec : -1e32f;
                sacc[j][r] = sc;
                tmax[r] = fmaxf(tmax[r], sc);
            }
        }
#pragma unroll
        for (int r = 0; r < 4; r++) {
            tmax[r] = fmaxf(tmax[r], __shfl_xor(tmax[r], 1, 64));
            tmax[r] = fmaxf(tmax[r], __shfl_xor(tmax[r], 2, 64));
            tmax[r] = fmaxf(tmax[r], __shfl_xor(tmax[r], 4, 64));
            tmax[r] = fmaxf(tmax[r], __shfl_xor(tmax[r], 8, 64));
        }
        float alpha[4], tsum[4];
#pragma unroll
        for (int r = 0; r < 4; r++) {
            float mnew = fmaxf(mrow[r], tmax[r]);
            alpha[r] = expf(mrow[r] - mnew);
            mrow[r]  = mnew;
            tsum[r]  = 0.f;
        }
#pragma unroll
        for (int j = 0; j < 4; j++)
#pragma unroll
            for (int r = 0; r < 4; r++) {
                float p = expf(sacc[j][r] - mrow[r]);
                ps[wave][quad * 4 + r][j * 16 + fr] = f2bf(p);
                tsum[r] += p;
            }
#pragma unroll
        for (int r = 0; r < 4; r++) {
            tsum[r] += __shfl_xor(tsum[r], 1, 64);
            tsum[r] += __shfl_xor(tsum[r], 2, 64);
            tsum[r] += __shfl_xor(tsum[r], 4, 64);
            tsum[r] += __shfl_xor(tsum[r], 8, 64);
            lrow[r] = lrow[r] * alpha[r] + tsum[r];
        }
        // rescale O
#pragma unroll
        for (int j2 = 0; j2 < 4; j2++)
#pragma unroll
            for (int r = 0; r < 4; r++)
                o[j2][r] *= alpha[r];
        // ---- O += P V  (P: A-operand rows fr; V^T: B-operand rows d) ----
        short8 pf0 = *(const short8*)&ps[wave][fr][quad * 8];
        short8 pf1 = *(const short8*)&ps[wave][fr][32 + quad * 8];
#pragma unroll
        for (int j2 = 0; j2 < 4; j2++) {
            const ushort_t* vr = vbase + (size_t)(j2 * 16 + fr) * T_LEN + kt0;
            short8 v0 = *(const short8*)(vr + quad * 8);
            short8 v1 = *(const short8*)(vr + 32 + quad * 8);
            o[j2] = __builtin_amdgcn_mfma_f32_16x16x32_bf16(pf0, v0, o[j2], 0, 0, 0);
            o[j2] = __builtin_amdgcn_mfma_f32_16x16x32_bf16(pf1, v1, o[j2], 0, 0, 0);
        }
    }

    // epilogue: divide by l, zero row q==0, scatter bf16
#pragma unroll
    for (int r = 0; r < 4; r++) {
        int qg = qr0 + quad * 4 + r;
        float linv = (qg == 0) ? 0.f : 1.f / lrow[r];
#pragma unroll
        for (int j2 = 0; j2 < 4; j2++) {
            attnc[((size_t)qg * B_SZ + b) * H_DIM + h * DHEAD + j2 * 16 + fr] =
                f2bf(o[j2][r] * linv);
        }
    }
}

// ---------------------------------------------------------------------------
// LN1: out1 = LN(x1);  writes fp32 + bf16
// ---------------------------------------------------------------------------
__global__ __launch_bounds__(256) void ln1_kernel(
    const float* __restrict__ X, const float* __restrict__ g,
    const float* __restrict__ bta, float* __restrict__ Y,
    ushort_t* __restrict__ Yb)
{
    int m    = blockIdx.x * 4 + (threadIdx.x >> 6);
    int lane = threadIdx.x & 63;
    const float* xr = X + (size_t)m * H_DIM;
    float x[8];
    float s = 0.f, ss = 0.f;
#pragma unroll
    for (int i = 0; i < 8; i++) {
        x[i] = xr[lane + 64 * i];
        s += x[i]; ss += x[i] * x[i];
    }
#pragma unroll
    for (int off = 32; off >= 1; off >>= 1) {
        s  += __shfl_xor(s,  off, 64);
        ss += __shfl_xor(ss, off, 64);
    }
    float mu  = s * (1.f / 512.f);
    float var = ss * (1.f / 512.f) - mu * mu;
    float rs  = rsqrtf(var + 1e-5f);
#pragma unroll
    for (int i = 0; i < 8; i++) {
        int c = lane + 64 * i;
        float v = (x[i] - mu) * rs * g[c] + bta[c];
        Y[(size_t)m * H_DIM + c]  = v;
        Yb[(size_t)m * H_DIM + c] = f2bf(v);
    }
}

// ---------------------------------------------------------------------------
// LN2 + residual: pred_bf[:, 0:512] = bf16(out1 + LN(f2))
// ---------------------------------------------------------------------------
__global__ __launch_bounds__(256) void ln2_kernel(
    const float* __restrict__ X, const float* __restrict__ g,
    const float* __restrict__ bta, const float* __restrict__ res,
    ushort_t* __restrict__ pred_bf)
{
    int m    = blockIdx.x * 4 + (threadIdx.x >> 6);
    int lane = threadIdx.x & 63;
    const float* xr = X + (size_t)m * H_DIM;
    float x[8];
    float s = 0.f, ss = 0.f;
#pragma unroll
    for (int i = 0; i < 8; i++) {
        x[i] = xr[lane + 64 * i];
        s += x[i]; ss += x[i] * x[i];
    }
#pragma unroll
    for (int off = 32; off >= 1; off >>= 1) {
        s  += __shfl_xor(s,  off, 64);
        ss += __shfl_xor(ss, off, 64);
    }
    float mu  = s * (1.f / 512.f);
    float var = ss * (1.f / 512.f) - mu * mu;
    float rs  = rsqrtf(var + 1e-5f);
    const float* rr = res + (size_t)m * H_DIM;
#pragma unroll
    for (int i = 0; i < 8; i++) {
        int c = lane + 64 * i;
        float v = (x[i] - mu) * rs * g[c] + bta[c] + rr[c];
        pred_bf[(size_t)m * P_DIM + c] = f2bf(v);
    }
}

// ---------------------------------------------------------------------------
// predot: lg[row] = dot(pred_bf[row,:], OW) + Ob  (one wave per row)
// ---------------------------------------------------------------------------
__global__ __launch_bounds__(256) void predot_kernel(
    const ushort_t* __restrict__ pred_bf, const float* __restrict__ OW,
    const float* __restrict__ Ob, float* __restrict__ lg)
{
    int m    = blockIdx.x * 4 + (threadIdx.x >> 6);
    int lane = threadIdx.x & 63;
    const ushort_t* pr = pred_bf + (size_t)m * P_DIM;
    float s = 0.f;
#pragma unroll 6
    for (int c = lane; c < P_DIM; c += 64)
        s = fmaf(bf2f(pr[c]), OW[c], s);
#pragma unroll
    for (int off = 32; off >= 1; off >>= 1) s += __shfl_xor(s, off, 64);
    if (lane == 0) lg[m] = s + Ob[0];
}

// ---------------------------------------------------------------------------
__global__ __launch_bounds__(256) void bce_kernel(
    const float* __restrict__ lg, const int* __restrict__ labels,
    const float* __restrict__ mask, float* __restrict__ accum)
{
    int m    = blockIdx.x * 256 + threadIdx.x;
    int lane = threadIdx.x & 63;
    float l  = lg[m];
    float y  = (float)labels[m];
    float mv = mask[m];
    float a  = (fmaxf(l, 0.f) - l * y + log1pf(expf(-fabsf(l)))) * mv;
#pragma unroll
    for (int off = 32; off >= 1; off >>= 1) {
        a  += __shfl_xor(a,  off, 64);
        mv += __shfl_xor(mv, off, 64);
    }
    if (lane == 0) {
        atomicAdd(accum,     a);
        atomicAdd(accum + 1, mv);
    }
}

__global__ void zero_accum(float* accum) { accum[0] = 0.f; accum[1] = 0.f; }

__global__ void finalize_kernel(const float* __restrict__ accum, float* __restrict__ out)
{
    out[0] = accum[0] / accum[1];
}

// ---------------------------------------------------------------------------
extern "C" void kernel_launch(void* const* d_in, const int* in_sizes, int n_in,
                              void* d_out, int out_size, void* d_ws, size_t ws_size,
                              hipStream_t stream)
{
    (void)in_sizes; (void)n_in; (void)out_size;
    const int*   ans    = (const int*)  d_in[0];
    const int*   cans   = (const int*)  d_in[1];
    const int*   labels = (const int*)  d_in[2];
    const float* mask   = (const float*)d_in[3];
    const int*   qids   = (const int*)  d_in[4];
    const int*   sids   = (const int*)  d_in[5];
    const float* smask  = (const float*)d_in[6];
    const float* Eq     = (const float*)d_in[7];
    const float* Es     = (const float*)d_in[8];
    const float* Ea     = (const float*)d_in[9];
    const float* El     = (const float*)d_in[10];
    const float* Wq     = (const float*)d_in[11];
    const float* bq     = (const float*)d_in[12];
    const float* Wk     = (const float*)d_in[13];
    const float* bk     = (const float*)d_in[14];
    const float* Wv     = (const float*)d_in[15];
    const float* bv     = (const float*)d_in[16];
    const float* Wo     = (const float*)d_in[17];
    const float* bo     = (const float*)d_in[18];
    const float* ln1_g  = (const float*)d_in[19];
    const float* ln1_b  = (const float*)d_in[20];
    const float* W1     = (const float*)d_in[21];
    const float* b1     = (const float*)d_in[22];
    const float* W2     = (const float*)d_in[23];
    const float* b2     = (const float*)d_in[24];
    const float* ln2_g  = (const float*)d_in[25];
    const float* ln2_b  = (const float*)d_in[26];
    const float* gammas = (const float*)d_in[27];
    const float* L1W    = (const float*)d_in[28];
    const float* L1b    = (const float*)d_in[29];
    const float* L2W    = (const float*)d_in[30];
    const float* L2b    = (const float*)d_in[31];
    const float* OW     = (const float*)d_in[32];
    const float* Ob     = (const float*)d_in[33];
    float* out = (float*)d_out;

    // Arena in units U = TB*64 floats (4 MiB). Peak usage 42U ≈ 176 MB.
    const size_t U = (size_t)TBTOK * 64;
    if (ws_size < 42 * U * sizeof(float)) return;
    float* ws = (float*)d_ws;
    ushort_t* wtb      = (ushort_t*)(ws);            // [0,3)  weights bf16 (perm)
    ushort_t* pred_bf  = (ushort_t*)(ws + 3 * U);    // [3,12) perm
    ushort_t* value_bf = (ushort_t*)(ws + 12 * U);   // [12,21) until V-gemm
    ushort_t* qb       = (ushort_t*)(ws + 21 * U);   // [21,25) until attn
    ushort_t* kb       = (ushort_t*)(ws + 25 * U);   // [25,29) until attn
    ushort_t* vtb      = (ushort_t*)(ws + 29 * U);   // [29,33) until attn
    ushort_t* attnc_bf = (ushort_t*)(ws + 33 * U);   // [33,37) until Wo
    float*    x1       = ws + 12 * U;                // [12,20) Wo-out / LN1-in
    float*    out1     = ws + 21 * U;                // [21,29) LN1..LN2
    ushort_t* out1_bf  = (ushort_t*)(ws + 29 * U);   // [29,33)
    ushort_t* f1_bf    = (ushort_t*)(ws + 12 * U);   // [12,16) W1-out
    float*    f2       = ws + 33 * U;                // [33,41) W2-out / LN2-in
    ushort_t* h1_bf    = (ushort_t*)(ws + 12 * U);   // [12,21) L1-out
    float*    lgits    = ws + 41 * U;                // TB floats
    float*    accum    = lgits + TBTOK;

    // bf16 weight arena offsets (elements)
    ushort_t* wq_b = wtb + 0;
    ushort_t* wk_b = wtb + 327680;
    ushort_t* wv_b = wtb + 655360;
    ushort_t* wo_b = wtb + 1245184;
    ushort_t* w1_b = wtb + 1507328;
    ushort_t* w2_b = wtb + 1769472;
    ushort_t* l1_b = wtb + 2031616;
    ushort_t* l2_b = wtb + 3358720;

    convert_weights<<<4576, 256, 0, stream>>>(Wq, Wk, Wv, Wo, W1, W2, L1W, L2W, wtb);
    embed_kernel<<<TBTOK, 256, 0, stream>>>(ans, cans, labels, mask, qids, sids,
                                            smask, Eq, Es, Ea, El, pred_bf, value_bf);
    // q,k,v projections (MFMA, bf16 scatter epilogues)
    mgemm<2><<<dim3(TBTOK/128, 4), 256, 0, stream>>>(
        pred_bf + 512, P_DIM, wq_b, 640, bq, nullptr, qb, 0, 640, nullptr, nullptr);
    mgemm<2><<<dim3(TBTOK/128, 4), 256, 0, stream>>>(
        pred_bf + 512, P_DIM, wk_b, 640, bk, nullptr, kb, 0, 640, nullptr, nullptr);
    mgemm<4><<<dim3(TBTOK/128, 4), 256, 0, stream>>>(
        value_bf, P_DIM, wv_b, P_DIM, bv, nullptr, vtb, 0, P_DIM, nullptr, nullptr);
    // attention (MFMA flash)
    attn_mfma<<<dim3(B_SZ * NHEAD, 8), 256, 0, stream>>>(
        qb, kb, vtb, mask, gammas, attnc_bf);
    // output projection -> x1 (fp32)
    mgemm<0><<<dim3(TBTOK/128, 4), 256, 0, stream>>>(
        attnc_bf, H_DIM, wo_b, H_DIM, bo, x1, nullptr, H_DIM, H_DIM, nullptr, nullptr);
    ln1_kernel<<<TBTOK/4, 256, 0, stream>>>(x1, ln1_g, ln1_b, out1, out1_bf);
    // FFN
    mgemm<1><<<dim3(TBTOK/128, 4), 256, 0, stream>>>(
        out1_bf, H_DIM, w1_b, H_DIM, b1, nullptr, f1_bf, H_DIM, H_DIM, nullptr, nullptr);
    mgemm<0><<<dim3(TBTOK/128, 4), 256, 0, stream>>>(
        f1_bf, H_DIM, w2_b, H_DIM, b2, f2, nullptr, H_DIM, H_DIM, nullptr, nullptr);
    ln2_kernel<<<TBTOK/4, 256, 0, stream>>>(f2, ln2_g, ln2_b, out1, pred_bf);
    // logits init = dot(pred, OW) + Ob
    zero_accum<<<1, 1, 0, stream>>>(accum);
    predot_kernel<<<TBTOK/4, 256, 0, stream>>>(pred_bf, OW, Ob, lgits);
    // L1 (relu, bf16 out)
    mgemm<1><<<dim3(TBTOK/128, 9), 256, 0, stream>>>(
        pred_bf, P_DIM, l1_b, P_DIM, L1b, nullptr, h1_bf, P_DIM, P_DIM, nullptr, nullptr);
    // L2 (relu) fused with OW dot -> atomics into lgits
    mgemm<3><<<dim3(TBTOK/128, 9), 256, 0, stream>>>(
        h1_bf, P_DIM, l2_b, P_DIM, L2b, nullptr, nullptr, 0, P_DIM, OW, lgits);
    // BCE + reduction
    bce_kernel<<<TBTOK/256, 256, 0, stream>>>(lgits, labels, mask, accum);
    finalize_kernel<<<1, 1, 0, stream>>>(accum, out);
}

// Round 5
// 534.156 us; speedup vs baseline: 4.7701x; 1.1806x over previous
//
#include <hip/hip_runtime.h>
#include <math.h>

// Problem constants
#define T_LEN 512
#define B_SZ  32
#define NHEAD 8
#define DHEAD 64
#define H_DIM 512
#define TBTOK 16384          // T*B
#define P_DIM 1152

typedef unsigned short ushort_t;
typedef short short8 __attribute__((ext_vector_type(8)));
typedef float f32x4 __attribute__((ext_vector_type(4)));

__device__ __forceinline__ ushort_t f2bf(float f) {
    union { float f; unsigned int u; } v; v.f = f;
    unsigned int r = v.u + 0x7fffu + ((v.u >> 16) & 1u);
    return (ushort_t)(r >> 16);
}
__device__ __forceinline__ float bf2f(ushort_t h) {
    union { unsigned int u; float f; } v; v.u = ((unsigned int)h) << 16;
    return v.f;
}
__device__ __forceinline__ void gload_lds16(const void* g, void* l) {
    __builtin_amdgcn_global_load_lds(
        (const __attribute__((address_space(1))) void*)g,
        (__attribute__((address_space(3))) void*)l, 16, 0, 0);
}

// ---------------------------------------------------------------------------
// Weight fp32 -> bf16 packing (all 8 matrices into one arena)
// ---------------------------------------------------------------------------
__global__ __launch_bounds__(256) void convert_weights(
    const float* __restrict__ wq, const float* __restrict__ wk,
    const float* __restrict__ wv, const float* __restrict__ wo,
    const float* __restrict__ w1, const float* __restrict__ w2,
    const float* __restrict__ l1, const float* __restrict__ l2,
    ushort_t* __restrict__ dst)
{
    const unsigned int offs[9] = {0u, 327680u, 655360u, 1245184u, 1507328u,
                                  1769472u, 2031616u, 3358720u, 4685824u};
    unsigned int c = (blockIdx.x * 256 + threadIdx.x) * 4;   // element offset
    const float* srcs[8] = {wq, wk, wv, wo, w1, w2, l1, l2};
    int s = 0;
#pragma unroll
    for (int i = 0; i < 7; i++) s += (c >= offs[i + 1]) ? 1 : 0;
    float4 v = *(const float4*)(srcs[s] + (c - offs[s]));
    ushort4 o;
    o.x = f2bf(v.x); o.y = f2bf(v.y); o.z = f2bf(v.z); o.w = f2bf(v.w);
    *(ushort4*)(dst + c) = o;
}

// ---------------------------------------------------------------------------
// Embedding / gather (bf16 outputs)
// ---------------------------------------------------------------------------
__global__ __launch_bounds__(256) void embed_kernel(
    const int* __restrict__ ans, const int* __restrict__ cans,
    const int* __restrict__ labels, const float* __restrict__ mask,
    const int* __restrict__ qids, const int* __restrict__ sids,
    const float* __restrict__ smask,
    const float* __restrict__ Eq, const float* __restrict__ Es,
    const float* __restrict__ Ea, const float* __restrict__ El,
    ushort_t* __restrict__ pred_bf, ushort_t* __restrict__ value_bf)
{
    int m = blockIdx.x;              // token = t*B + b
    int tid = threadIdx.x;           // 256
    float mval = mask[m];
    int qid = qids[m];
    int a   = ans[m] - 1;
    int ca  = cans[m] - 1;
    int lb  = labels[m];
    ushort_t* pr = pred_bf  + (size_t)m * P_DIM;
    ushort_t* vr = value_bf + (size_t)m * P_DIM;

    if (tid < 128) {
        ushort_t qv = f2bf(Eq[(size_t)qid * 128 + tid]);
        pr[512 + tid] = qv;
        vr[768 + tid] = qv;
    }
    int d = tid;                     // 0..255
    float s = 0.f;
#pragma unroll
    for (int j = 0; j < 8; j++) {
        int  sid = sids[m * 8 + j];
        float sm = smask[m * 8 + j];
        s += Es[(size_t)sid * 256 + d] * sm;
    }
    ushort_t sb = f2bf(s);
    pr[640 + d] = sb;
    vr[896 + d] = sb;
    ushort_t cab = f2bf(Ea[ca * 256 + d]);
    pr[896 + d] = cab;
    vr[512 + d] = cab;
    vr[256 + d] = f2bf(Ea[a * 256 + d] * mval);
    vr[0   + d] = f2bf(El[lb * 256 + d] * mval);
}

// ---------------------------------------------------------------------------
// MFMA bf16 GEMM: C(M x N) = A(M x K bf16) @ W(N x K bf16)^T + bias
// 128x128 tile, 256 thr (4 waves, 2x2 of 64x64), BK=32, 16x16x32 MFMA.
// All epilogues write bf16, coalesced via per-wave LDS transpose stage.
// MODE 1: row-major store (RELU optional)
// MODE 2: qk scatter [bh][t][d]
// MODE 3: relu, dot with OW, atomicAdd into lg[row] (no store)
// MODE 4: V^T scatter [bh][d][t]; A rows consumed in (b,t)-permuted order
// ---------------------------------------------------------------------------
template<int MODE, bool RELU>
__global__ __launch_bounds__(256) void mgemm(
    const ushort_t* __restrict__ A, int lda,
    const ushort_t* __restrict__ W, int ldw,
    const float* __restrict__ bias,
    ushort_t* __restrict__ Cb, int ldc, int K,
    const float* __restrict__ OW, float* __restrict__ lg)
{
    __shared__ __align__(16) ushort_t As[128 * 32];
    __shared__ __align__(16) ushort_t Ws[128 * 32];
    __shared__ __align__(16) ushort_t et[4][64][72];   // epilogue stage

    const int m0 = blockIdx.x * 128;
    const int n0 = blockIdx.y * 128;
    const int tid  = threadIdx.x;
    const int wave = tid >> 6;
    const int lane = tid & 63;
    const int wm = wave & 1, wn = wave >> 1;

    f32x4 acc[4][4] = {};

    const int srow   = lane >> 2;
    const int schunk = (lane & 3) * 8;
    int arowA, arowB;
    if (MODE == 4) {
        int mA = m0 + wave * 32 + srow;        // output m = b*512 + t
        int mB = mA + 16;
        arowA = ((mA & 511) << 5) + (mA >> 9); // actual token row t*32+b
        arowB = ((mB & 511) << 5) + (mB >> 9);
    } else {
        arowA = m0 + wave * 32 + srow;
        arowB = arowA + 16;
    }
    const ushort_t* Ag0 = A + (size_t)arowA * lda + schunk;
    const ushort_t* Ag1 = A + (size_t)arowB * lda + schunk;
    const ushort_t* Wg0 = W + (size_t)(n0 + wave * 32 + srow) * ldw + schunk;
    const ushort_t* Wg1 = Wg0 + (size_t)16 * ldw;
    ushort_t* Al0 = &As[(wave * 32) * 32];
    ushort_t* Al1 = &As[(wave * 32 + 16) * 32];
    ushort_t* Wl0 = &Ws[(wave * 32) * 32];
    ushort_t* Wl1 = &Ws[(wave * 32 + 16) * 32];

    const int fr   = lane & 15;      // fragment row(A)/col(B)
    const int quad = lane >> 4;

    for (int k0 = 0; k0 < K; k0 += 32) {
        gload_lds16(Ag0 + k0, Al0);
        gload_lds16(Ag1 + k0, Al1);
        gload_lds16(Wg0 + k0, Wl0);
        gload_lds16(Wg1 + k0, Wl1);
        __syncthreads();
        short8 af[4], wf[4];
#pragma unroll
        for (int i = 0; i < 4; i++)
            af[i] = *(const short8*)&As[(wm * 64 + i * 16 + fr) * 32 + quad * 8];
#pragma unroll
        for (int j = 0; j < 4; j++)
            wf[j] = *(const short8*)&Ws[(wn * 64 + j * 16 + fr) * 32 + quad * 8];
#pragma unroll
        for (int i = 0; i < 4; i++)
#pragma unroll
            for (int j = 0; j < 4; j++)
                acc[i][j] = __builtin_amdgcn_mfma_f32_16x16x32_bf16(
                    af[i], wf[j], acc[i][j], 0, 0, 0);
        __syncthreads();
    }

    // C/D layout: col = lane&15, row = quad*4 + reg (per 16x16 frag)
    if (MODE == 3) {
#pragma unroll
        for (int i = 0; i < 4; i++)
#pragma unroll
            for (int r = 0; r < 4; r++) {
                int row = m0 + wm * 64 + i * 16 + quad * 4 + r;
                float part = 0.f;
#pragma unroll
                for (int j = 0; j < 4; j++) {
                    int col = n0 + wn * 64 + j * 16 + fr;
                    float v = fmaxf(acc[i][j][r] + bias[col], 0.f);
                    part = fmaf(v, OW[col], part);
                }
                part += __shfl_xor(part, 1, 64);
                part += __shfl_xor(part, 2, 64);
                part += __shfl_xor(part, 4, 64);
                part += __shfl_xor(part, 8, 64);
                if (fr == 0) atomicAdd(&lg[row], part);
            }
        return;
    }

    // stage bf16 tile into wave-private LDS (no barrier needed)
#pragma unroll
    for (int i = 0; i < 4; i++)
#pragma unroll
        for (int r = 0; r < 4; r++) {
            int rl = i * 16 + quad * 4 + r;          // row local 0..63
#pragma unroll
            for (int j = 0; j < 4; j++) {
                int cl = j * 16 + fr;                // col local 0..63
                float v = acc[i][j][r] + bias[n0 + wn * 64 + cl];
                if (RELU) v = fmaxf(v, 0.f);
                if (MODE == 4) et[wave][cl][rl] = f2bf(v);
                else           et[wave][rl][cl] = f2bf(v);
            }
        }

    // coalesced readback + store: 8 lanes per stage-row -> 128B runs
    const int sub8 = (lane & 7) * 8;
    const int grp  = lane >> 3;                      // 0..7
#pragma unroll
    for (int rr = 0; rr < 8; rr++) {
        int rowl = rr * 8 + grp;                     // stage row 0..63
        short8 val = *(const short8*)&et[wave][rowl][sub8];
        if (MODE == 1) {
            int row = m0 + wm * 64 + rowl;
            int col = n0 + wn * 64 + sub8;
            *(short8*)&Cb[(size_t)row * ldc + col] = val;
        } else if (MODE == 2) {
            int row = m0 + wm * 64 + rowl;           // t*32 + b
            int t = row >> 5, b = row & 31;
            int h = (n0 + wn * 64) >> 6;
            *(short8*)&Cb[(((size_t)(b * 8 + h)) << 15) + ((size_t)t << 6) + sub8] = val;
        } else { // MODE 4: stage row = output col (d), stage col = m (b*512+t)
            int m = m0 + wm * 64 + sub8;             // 8 consecutive t, same b
            int b = m >> 9, t = m & 511;
            int h = (n0 + wn * 64) >> 6;
            int d = rowl;
            *(short8*)&Cb[(((size_t)(b * 8 + h)) << 15) + ((size_t)d << 9) + t] = val;
        }
    }
}

// ---------------------------------------------------------------------------
// MFMA flash attention. grid = (B*NH, 8 reversed q-tiles), 256 threads.
// qb,kb: bf16 [bh][t][64]; vtb: bf16 [bh][d][512].
// Output bf16 attnc[(t*B+b)*512 + h*64 + d], coalesced via ps stage.
// ---------------------------------------------------------------------------
__global__ __launch_bounds__(256) void attn_mfma(
    const ushort_t* __restrict__ qb, const ushort_t* __restrict__ kb,
    const ushort_t* __restrict__ vtb, const float* __restrict__ mask,
    const float* __restrict__ gammas, ushort_t* __restrict__ attnc)
{
    __shared__ __align__(16) ushort_t ps[4][16][72];   // P / O stage, per wave
    __shared__ float decay[512];
    __shared__ float mcol[512];

    const int bh  = blockIdx.x;          // b*8 + h
    const int b   = bh >> 3;
    const int h   = bh & 7;
    const int qt0 = (7 - blockIdx.y) * 64;   // heavy tiles first
    const int tid  = threadIdx.x;
    const int wave = tid >> 6;
    const int lane = tid & 63;
    const int fr   = lane & 15;
    const int quad = lane >> 4;

    {   // decay LUT + mask column for this (h, b)
        float g  = gammas[h];
        float sp = (g > 20.f) ? g : log1pf(expf(g));
        for (int i = tid; i < 512; i += 256) {
            decay[i] = fmaxf(expf(-sp * sqrtf((float)i)), 1e-5f);
            mcol[i]  = mask[(size_t)i * B_SZ + b];
        }
    }
    __syncthreads();

    const int qr0 = qt0 + wave * 16;
    const ushort_t* qbase = qb  + ((size_t)bh << 15);   // [t][64]
    const ushort_t* kbase = kb  + ((size_t)bh << 15);
    const ushort_t* vbase = vtb + ((size_t)bh << 15);   // [d][512]

    short8 af0 = *(const short8*)(qbase + (size_t)(qr0 + fr) * 64 + quad * 8);
    short8 af1 = *(const short8*)(qbase + (size_t)(qr0 + fr) * 64 + 32 + quad * 8);

    f32x4 o[4] = {};                       // O[q=quad*4+r][d=j2*16+fr]
    float mrow[4] = {-3e38f, -3e38f, -3e38f, -3e38f};
    float lrow[4] = {0.f, 0.f, 0.f, 0.f};

    for (int kt0 = 0; kt0 <= qt0; kt0 += 64) {
        f32x4 sacc[4] = {};
#pragma unroll
        for (int j = 0; j < 4; j++) {
            const ushort_t* kr = kbase + (size_t)(kt0 + j * 16 + fr) * 64;
            short8 k0 = *(const short8*)(kr + quad * 8);
            short8 k1 = *(const short8*)(kr + 32 + quad * 8);
            sacc[j] = __builtin_amdgcn_mfma_f32_16x16x32_bf16(af0, k0, sacc[j], 0, 0, 0);
            sacc[j] = __builtin_amdgcn_mfma_f32_16x16x32_bf16(af1, k1, sacc[j], 0, 0, 0);
        }
        float tmax[4] = {-3e38f, -3e38f, -3e38f, -3e38f};
#pragma unroll
        for (int j = 0; j < 4; j++) {
            int kg = kt0 + j * 16 + fr;
            float km = mcol[kg];
#pragma unroll
            for (int r = 0; r < 4; r++) {
                int qg = qr0 + quad * 4 + r;
                float sc = sacc[j][r] * 0.125f;
                if (km == 0.f) sc = -1e32f;
                int didx = qg - kg;
                float dec = decay[didx < 0 ? 0 : didx];
                sc = (kg < qg) ? sc * dec : -1e32f;
                sacc[j][r] = sc;
                tmax[r] = fmaxf(tmax[r], sc);
            }
        }
#pragma unroll
        for (int r = 0; r < 4; r++) {
            tmax[r] = fmaxf(tmax[r], __shfl_xor(tmax[r], 1, 64));
            tmax[r] = fmaxf(tmax[r], __shfl_xor(tmax[r], 2, 64));
            tmax[r] = fmaxf(tmax[r], __shfl_xor(tmax[r], 4, 64));
            tmax[r] = fmaxf(tmax[r], __shfl_xor(tmax[r], 8, 64));
        }
        float alpha[4], tsum[4];
#pragma unroll
        for (int r = 0; r < 4; r++) {
            float mnew = fmaxf(mrow[r], tmax[r]);
            alpha[r] = expf(mrow[r] - mnew);
            mrow[r]  = mnew;
            tsum[r]  = 0.f;
        }
#pragma unroll
        for (int j = 0; j < 4; j++)
#pragma unroll
            for (int r = 0; r < 4; r++) {
                float p = expf(sacc[j][r] - mrow[r]);
                ps[wave][quad * 4 + r][j * 16 + fr] = f2bf(p);
                tsum[r] += p;
            }
#pragma unroll
        for (int r = 0; r < 4; r++) {
            tsum[r] += __shfl_xor(tsum[r], 1, 64);
            tsum[r] += __shfl_xor(tsum[r], 2, 64);
            tsum[r] += __shfl_xor(tsum[r], 4, 64);
            tsum[r] += __shfl_xor(tsum[r], 8, 64);
            lrow[r] = lrow[r] * alpha[r] + tsum[r];
        }
#pragma unroll
        for (int j2 = 0; j2 < 4; j2++)
#pragma unroll
            for (int r = 0; r < 4; r++)
                o[j2][r] *= alpha[r];
        short8 pf0 = *(const short8*)&ps[wave][fr][quad * 8];
        short8 pf1 = *(const short8*)&ps[wave][fr][32 + quad * 8];
#pragma unroll
        for (int j2 = 0; j2 < 4; j2++) {
            const ushort_t* vr = vbase + (size_t)(j2 * 16 + fr) * T_LEN + kt0;
            short8 v0 = *(const short8*)(vr + quad * 8);
            short8 v1 = *(const short8*)(vr + 32 + quad * 8);
            o[j2] = __builtin_amdgcn_mfma_f32_16x16x32_bf16(pf0, v0, o[j2], 0, 0, 0);
            o[j2] = __builtin_amdgcn_mfma_f32_16x16x32_bf16(pf1, v1, o[j2], 0, 0, 0);
        }
    }

    // epilogue: divide by l, zero row q==0, stage + coalesced store
#pragma unroll
    for (int r = 0; r < 4; r++) {
        int qg = qr0 + quad * 4 + r;
        float linv = (qg == 0) ? 0.f : 1.f / lrow[r];
#pragma unroll
        for (int j2 = 0; j2 < 4; j2++)
            ps[wave][quad * 4 + r][j2 * 16 + fr] = f2bf(o[j2][r] * linv);
    }
    const int sub8 = (lane & 7) * 8;
    const int grp  = lane >> 3;
#pragma unroll
    for (int half = 0; half < 2; half++) {
        int rowl = half * 8 + grp;                   // 0..15
        short8 val = *(const short8*)&ps[wave][rowl][sub8];
        int qg = qr0 + rowl;
        *(short8*)&attnc[((size_t)qg * B_SZ + b) * H_DIM + h * DHEAD + sub8] = val;
    }
}

// ---------------------------------------------------------------------------
// LN1: reads bf16 X, writes out1 fp32 + bf16
// ---------------------------------------------------------------------------
__global__ __launch_bounds__(256) void ln1_kernel(
    const ushort_t* __restrict__ X, const float* __restrict__ g,
    const float* __restrict__ bta, float* __restrict__ Y,
    ushort_t* __restrict__ Yb)
{
    int m    = blockIdx.x * 4 + (threadIdx.x >> 6);
    int lane = threadIdx.x & 63;
    int c0   = lane * 8;
    const ushort_t* xr = X + (size_t)m * H_DIM + c0;
    float x[8];
    float s = 0.f, ss = 0.f;
    short8 xv = *(const short8*)xr;
#pragma unroll
    for (int i = 0; i < 8; i++) {
        x[i] = bf2f((ushort_t)xv[i]);
        s += x[i]; ss += x[i] * x[i];
    }
#pragma unroll
    for (int off = 32; off >= 1; off >>= 1) {
        s  += __shfl_xor(s,  off, 64);
        ss += __shfl_xor(ss, off, 64);
    }
    float mu  = s * (1.f / 512.f);
    float var = ss * (1.f / 512.f) - mu * mu;
    float rs  = rsqrtf(var + 1e-5f);
    float  yo[8];
    ushort_t yb[8];
#pragma unroll
    for (int i = 0; i < 8; i++) {
        float v = (x[i] - mu) * rs * g[c0 + i] + bta[c0 + i];
        yo[i] = v; yb[i] = f2bf(v);
    }
    *(float4*)(Y + (size_t)m * H_DIM + c0)     = *(float4*)&yo[0];
    *(float4*)(Y + (size_t)m * H_DIM + c0 + 4) = *(float4*)&yo[4];
    *(short8*)(Yb + (size_t)m * H_DIM + c0)    = *(short8*)&yb[0];
}

// ---------------------------------------------------------------------------
// LN2 + residual: pred_bf[:, 0:512] = bf16(out1 + LN(f2)); f2 is bf16
// ---------------------------------------------------------------------------
__global__ __launch_bounds__(256) void ln2_kernel(
    const ushort_t* __restrict__ X, const float* __restrict__ g,
    const float* __restrict__ bta, const float* __restrict__ res,
    ushort_t* __restrict__ pred_bf)
{
    int m    = blockIdx.x * 4 + (threadIdx.x >> 6);
    int lane = threadIdx.x & 63;
    int c0   = lane * 8;
    const ushort_t* xr = X + (size_t)m * H_DIM + c0;
    float x[8];
    float s = 0.f, ss = 0.f;
    short8 xv = *(const short8*)xr;
#pragma unroll
    for (int i = 0; i < 8; i++) {
        x[i] = bf2f((ushort_t)xv[i]);
        s += x[i]; ss += x[i] * x[i];
    }
#pragma unroll
    for (int off = 32; off >= 1; off >>= 1) {
        s  += __shfl_xor(s,  off, 64);
        ss += __shfl_xor(ss, off, 64);
    }
    float mu  = s * (1.f / 512.f);
    float var = ss * (1.f / 512.f) - mu * mu;
    float rs  = rsqrtf(var + 1e-5f);
    float4 r0 = *(const float4*)(res + (size_t)m * H_DIM + c0);
    float4 r1 = *(const float4*)(res + (size_t)m * H_DIM + c0 + 4);
    float rr[8] = {r0.x, r0.y, r0.z, r0.w, r1.x, r1.y, r1.z, r1.w};
    ushort_t yb[8];
#pragma unroll
    for (int i = 0; i < 8; i++)
        yb[i] = f2bf((x[i] - mu) * rs * g[c0 + i] + bta[c0 + i] + rr[i]);
    *(short8*)(pred_bf + (size_t)m * P_DIM + c0) = *(short8*)&yb[0];
}

// ---------------------------------------------------------------------------
// predot: lg[row] = dot(pred_bf[row,:], OW) + Ob  (one wave per row)
// ---------------------------------------------------------------------------
__global__ __launch_bounds__(256) void predot_kernel(
    const ushort_t* __restrict__ pred_bf, const float* __restrict__ OW,
    const float* __restrict__ Ob, float* __restrict__ lg)
{
    int m    = blockIdx.x * 4 + (threadIdx.x >> 6);
    int lane = threadIdx.x & 63;
    const ushort_t* pr = pred_bf + (size_t)m * P_DIM;
    float s = 0.f;
#pragma unroll 6
    for (int c = lane; c < P_DIM; c += 64)
        s = fmaf(bf2f(pr[c]), OW[c], s);
#pragma unroll
    for (int off = 32; off >= 1; off >>= 1) s += __shfl_xor(s, off, 64);
    if (lane == 0) lg[m] = s + Ob[0];
}

// ---------------------------------------------------------------------------
__global__ __launch_bounds__(256) void bce_kernel(
    const float* __restrict__ lg, const int* __restrict__ labels,
    const float* __restrict__ mask, float* __restrict__ accum)
{
    int m    = blockIdx.x * 256 + threadIdx.x;
    int lane = threadIdx.x & 63;
    float l  = lg[m];
    float y  = (float)labels[m];
    float mv = mask[m];
    float a  = (fmaxf(l, 0.f) - l * y + log1pf(expf(-fabsf(l)))) * mv;
#pragma unroll
    for (int off = 32; off >= 1; off >>= 1) {
        a  += __shfl_xor(a,  off, 64);
        mv += __shfl_xor(mv, off, 64);
    }
    if (lane == 0) {
        atomicAdd(accum,     a);
        atomicAdd(accum + 1, mv);
    }
}

__global__ void zero_accum(float* accum) { accum[0] = 0.f; accum[1] = 0.f; }

__global__ void finalize_kernel(const float* __restrict__ accum, float* __restrict__ out)
{
    out[0] = accum[0] / accum[1];
}

// ---------------------------------------------------------------------------
extern "C" void kernel_launch(void* const* d_in, const int* in_sizes, int n_in,
                              void* d_out, int out_size, void* d_ws, size_t ws_size,
                              hipStream_t stream)
{
    (void)in_sizes; (void)n_in; (void)out_size;
    const int*   ans    = (const int*)  d_in[0];
    const int*   cans   = (const int*)  d_in[1];
    const int*   labels = (const int*)  d_in[2];
    const float* mask   = (const float*)d_in[3];
    const int*   qids   = (const int*)  d_in[4];
    const int*   sids   = (const int*)  d_in[5];
    const float* smask  = (const float*)d_in[6];
    const float* Eq     = (const float*)d_in[7];
    const float* Es     = (const float*)d_in[8];
    const float* Ea     = (const float*)d_in[9];
    const float* El     = (const float*)d_in[10];
    const float* Wq     = (const float*)d_in[11];
    const float* bq     = (const float*)d_in[12];
    const float* Wk     = (const float*)d_in[13];
    const float* bk     = (const float*)d_in[14];
    const float* Wv     = (const float*)d_in[15];
    const float* bv     = (const float*)d_in[16];
    const float* Wo     = (const float*)d_in[17];
    const float* bo     = (const float*)d_in[18];
    const float* ln1_g  = (const float*)d_in[19];
    const float* ln1_b  = (const float*)d_in[20];
    const float* W1     = (const float*)d_in[21];
    const float* b1     = (const float*)d_in[22];
    const float* W2     = (const float*)d_in[23];
    const float* b2     = (const float*)d_in[24];
    const float* ln2_g  = (const float*)d_in[25];
    const float* ln2_b  = (const float*)d_in[26];
    const float* gammas = (const float*)d_in[27];
    const float* L1W    = (const float*)d_in[28];
    const float* L1b    = (const float*)d_in[29];
    const float* L2W    = (const float*)d_in[30];
    const float* L2b    = (const float*)d_in[31];
    const float* OW     = (const float*)d_in[32];
    const float* Ob     = (const float*)d_in[33];
    float* out = (float*)d_out;

    // Arena in units U = TB*64 floats (4 MiB). Peak 42U ≈ 176 MB.
    const size_t U = (size_t)TBTOK * 64;
    if (ws_size < 42 * U * sizeof(float)) return;
    float* ws = (float*)d_ws;
    ushort_t* wtb      = (ushort_t*)(ws);            // [0,3)  weights bf16 (perm)
    ushort_t* pred_bf  = (ushort_t*)(ws + 3 * U);    // [3,12) perm
    ushort_t* value_bf = (ushort_t*)(ws + 12 * U);   // [12,21) until V-gemm
    ushort_t* qb       = (ushort_t*)(ws + 21 * U);   // [21,25) until attn
    ushort_t* kb       = (ushort_t*)(ws + 25 * U);   // [25,29) until attn
    ushort_t* vtb      = (ushort_t*)(ws + 29 * U);   // [29,33) until attn
    ushort_t* attnc_bf = (ushort_t*)(ws + 33 * U);   // [33,37) until Wo
    ushort_t* x1_bf    = (ushort_t*)(ws + 12 * U);   // [12,16) Wo-out / LN1-in
    float*    out1     = ws + 16 * U;                // [16,24) LN1..LN2 fp32
    ushort_t* out1_bf  = (ushort_t*)(ws + 24 * U);   // [24,28)
    ushort_t* f1_bf    = (ushort_t*)(ws + 28 * U);   // [28,32) W1-out
    ushort_t* f2_bf    = (ushort_t*)(ws + 32 * U);   // [32,36) W2-out / LN2-in
    ushort_t* h1_bf    = (ushort_t*)(ws + 12 * U);   // [12,21) L1-out
    float*    lgits    = ws + 41 * U;                // TB floats
    float*    accum    = lgits + TBTOK;

    // bf16 weight arena offsets (elements)
    ushort_t* wq_b = wtb + 0;
    ushort_t* wk_b = wtb + 327680;
    ushort_t* wv_b = wtb + 655360;
    ushort_t* wo_b = wtb + 1245184;
    ushort_t* w1_b = wtb + 1507328;
    ushort_t* w2_b = wtb + 1769472;
    ushort_t* l1_b = wtb + 2031616;
    ushort_t* l2_b = wtb + 3358720;

    convert_weights<<<4576, 256, 0, stream>>>(Wq, Wk, Wv, Wo, W1, W2, L1W, L2W, wtb);
    embed_kernel<<<TBTOK, 256, 0, stream>>>(ans, cans, labels, mask, qids, sids,
                                            smask, Eq, Es, Ea, El, pred_bf, value_bf);
    // q,k,v projections (MFMA, coalesced bf16 scatter epilogues)
    mgemm<2,false><<<dim3(TBTOK/128, 4), 256, 0, stream>>>(
        pred_bf + 512, P_DIM, wq_b, 640, bq, qb, 0, 640, nullptr, nullptr);
    mgemm<2,false><<<dim3(TBTOK/128, 4), 256, 0, stream>>>(
        pred_bf + 512, P_DIM, wk_b, 640, bk, kb, 0, 640, nullptr, nullptr);
    mgemm<4,false><<<dim3(TBTOK/128, 4), 256, 0, stream>>>(
        value_bf, P_DIM, wv_b, P_DIM, bv, vtb, 0, P_DIM, nullptr, nullptr);
    // attention (MFMA flash)
    attn_mfma<<<dim3(B_SZ * NHEAD, 8), 256, 0, stream>>>(
        qb, kb, vtb, mask, gammas, attnc_bf);
    // output projection -> x1_bf
    mgemm<1,false><<<dim3(TBTOK/128, 4), 256, 0, stream>>>(
        attnc_bf, H_DIM, wo_b, H_DIM, bo, x1_bf, H_DIM, H_DIM, nullptr, nullptr);
    ln1_kernel<<<TBTOK/4, 256, 0, stream>>>(x1_bf, ln1_g, ln1_b, out1, out1_bf);
    // FFN
    mgemm<1,true><<<dim3(TBTOK/128, 4), 256, 0, stream>>>(
        out1_bf, H_DIM, w1_b, H_DIM, b1, f1_bf, H_DIM, H_DIM, nullptr, nullptr);
    mgemm<1,false><<<dim3(TBTOK/128, 4), 256, 0, stream>>>(
        f1_bf, H_DIM, w2_b, H_DIM, b2, f2_bf, H_DIM, H_DIM, nullptr, nullptr);
    ln2_kernel<<<TBTOK/4, 256, 0, stream>>>(f2_bf, ln2_g, ln2_b, out1, pred_bf);
    // logits init = dot(pred, OW) + Ob
    zero_accum<<<1, 1, 0, stream>>>(accum);
    predot_kernel<<<TBTOK/4, 256, 0, stream>>>(pred_bf, OW, Ob, lgits);
    // L1 (relu)
    mgemm<1,true><<<dim3(TBTOK/128, 9), 256, 0, stream>>>(
        pred_bf, P_DIM, l1_b, P_DIM, L1b, h1_bf, P_DIM, P_DIM, nullptr, nullptr);
    // L2 (relu) fused with OW dot -> atomics into lgits
    mgemm<3,true><<<dim3(TBTOK/128, 9), 256, 0, stream>>>(
        h1_bf, P_DIM, l2_b, P_DIM, L2b, nullptr, 0, P_DIM, OW, lgits);
    // BCE + reduction
    bce_kernel<<<TBTOK/256, 256, 0, stream>>>(lgits, labels, mask, accum);
    finalize_kernel<<<1, 1, 0, stream>>>(accum, out);
}

// Round 6
// 526.582 us; speedup vs baseline: 4.8387x; 1.0144x over previous
//
#include <hip/hip_runtime.h>
#include <math.h>

// Problem constants
#define T_LEN 512
#define B_SZ  32
#define NHEAD 8
#define DHEAD 64
#define H_DIM 512
#define TBTOK 16384          // T*B
#define P_DIM 1152

typedef unsigned short ushort_t;
typedef short short8 __attribute__((ext_vector_type(8)));
typedef float f32x4 __attribute__((ext_vector_type(4)));

__device__ __forceinline__ ushort_t f2bf(float f) {
    union { float f; unsigned int u; } v; v.f = f;
    unsigned int r = v.u + 0x7fffu + ((v.u >> 16) & 1u);
    return (ushort_t)(r >> 16);
}
__device__ __forceinline__ float bf2f(ushort_t h) {
    union { unsigned int u; float f; } v; v.u = ((unsigned int)h) << 16;
    return v.f;
}
__device__ __forceinline__ void gload_lds16(const void* g, void* l) {
    __builtin_amdgcn_global_load_lds(
        (const __attribute__((address_space(1))) void*)g,
        (__attribute__((address_space(3))) void*)l, 16, 0, 0);
}

// ---------------------------------------------------------------------------
// Weight fp32 -> bf16 packing (all 8 matrices into one arena)
// ---------------------------------------------------------------------------
__global__ __launch_bounds__(256) void convert_weights(
    const float* __restrict__ wq, const float* __restrict__ wk,
    const float* __restrict__ wv, const float* __restrict__ wo,
    const float* __restrict__ w1, const float* __restrict__ w2,
    const float* __restrict__ l1, const float* __restrict__ l2,
    ushort_t* __restrict__ dst)
{
    const unsigned int offs[9] = {0u, 327680u, 655360u, 1245184u, 1507328u,
                                  1769472u, 2031616u, 3358720u, 4685824u};
    unsigned int c = (blockIdx.x * 256 + threadIdx.x) * 4;   // element offset
    const float* srcs[8] = {wq, wk, wv, wo, w1, w2, l1, l2};
    int s = 0;
#pragma unroll
    for (int i = 0; i < 7; i++) s += (c >= offs[i + 1]) ? 1 : 0;
    float4 v = *(const float4*)(srcs[s] + (c - offs[s]));
    ushort4 o;
    o.x = f2bf(v.x); o.y = f2bf(v.y); o.z = f2bf(v.z); o.w = f2bf(v.w);
    *(ushort4*)(dst + c) = o;
}

// ---------------------------------------------------------------------------
// Embedding / gather (bf16 outputs)
// ---------------------------------------------------------------------------
__global__ __launch_bounds__(256) void embed_kernel(
    const int* __restrict__ ans, const int* __restrict__ cans,
    const int* __restrict__ labels, const float* __restrict__ mask,
    const int* __restrict__ qids, const int* __restrict__ sids,
    const float* __restrict__ smask,
    const float* __restrict__ Eq, const float* __restrict__ Es,
    const float* __restrict__ Ea, const float* __restrict__ El,
    ushort_t* __restrict__ pred_bf, ushort_t* __restrict__ value_bf)
{
    int m = blockIdx.x;              // token = t*B + b
    int tid = threadIdx.x;           // 256
    float mval = mask[m];
    int qid = qids[m];
    int a   = ans[m] - 1;
    int ca  = cans[m] - 1;
    int lb  = labels[m];
    ushort_t* pr = pred_bf  + (size_t)m * P_DIM;
    ushort_t* vr = value_bf + (size_t)m * P_DIM;

    if (tid < 128) {
        ushort_t qv = f2bf(Eq[(size_t)qid * 128 + tid]);
        pr[512 + tid] = qv;
        vr[768 + tid] = qv;
    }
    int d = tid;                     // 0..255
    float s = 0.f;
#pragma unroll
    for (int j = 0; j < 8; j++) {
        int  sid = sids[m * 8 + j];
        float sm = smask[m * 8 + j];
        s += Es[(size_t)sid * 256 + d] * sm;
    }
    ushort_t sb = f2bf(s);
    pr[640 + d] = sb;
    vr[896 + d] = sb;
    ushort_t cab = f2bf(Ea[ca * 256 + d]);
    pr[896 + d] = cab;
    vr[512 + d] = cab;
    vr[256 + d] = f2bf(Ea[a * 256 + d] * mval);
    vr[0   + d] = f2bf(El[lb * 256 + d] * mval);
}

// ---------------------------------------------------------------------------
// MFMA bf16 GEMM: C(M x N) = A(M x K bf16) @ W(N x K bf16)^T + bias
// 128x128 tile, 256 thr (4 waves, 2x2 of 64x64), BK=32, 16x16x32 MFMA.
// MODE 1: row-major bf16 store (RELU optional)
// MODE 3: relu, dot with OW, atomicAdd into lg[row] (no store)
// MODE 4: V^T scatter [bh][d][t]; A rows consumed in (b,t)-permuted order
// MODE 5: merged Q|K scatter [bh][t][d]; cols<512 -> Cb (scaled 1/8, bias),
//         cols>=512 -> Cb2 (bias2)
// ---------------------------------------------------------------------------
template<int MODE, bool RELU>
__global__ __launch_bounds__(256) void mgemm(
    const ushort_t* __restrict__ A, int lda,
    const ushort_t* __restrict__ W, int ldw,
    const float* __restrict__ bias, const float* __restrict__ bias2,
    ushort_t* __restrict__ Cb, ushort_t* __restrict__ Cb2, int ldc, int K,
    const float* __restrict__ OW, float* __restrict__ lg)
{
    __shared__ __align__(16) ushort_t As[128 * 32];
    __shared__ __align__(16) ushort_t Ws[128 * 32];
    __shared__ __align__(16) ushort_t et[4][64][72];   // epilogue stage

    const int m0 = blockIdx.x * 128;
    const int n0 = blockIdx.y * 128;
    const int tid  = threadIdx.x;
    const int wave = tid >> 6;
    const int lane = tid & 63;
    const int wm = wave & 1, wn = wave >> 1;

    f32x4 acc[4][4] = {};

    const int srow   = lane >> 2;
    const int schunk = (lane & 3) * 8;
    int arowA, arowB;
    if (MODE == 4) {
        int mA = m0 + wave * 32 + srow;        // output m = b*512 + t
        int mB = mA + 16;
        arowA = ((mA & 511) << 5) + (mA >> 9); // actual token row t*32+b
        arowB = ((mB & 511) << 5) + (mB >> 9);
    } else {
        arowA = m0 + wave * 32 + srow;
        arowB = arowA + 16;
    }
    const ushort_t* Ag0 = A + (size_t)arowA * lda + schunk;
    const ushort_t* Ag1 = A + (size_t)arowB * lda + schunk;
    const ushort_t* Wg0 = W + (size_t)(n0 + wave * 32 + srow) * ldw + schunk;
    const ushort_t* Wg1 = Wg0 + (size_t)16 * ldw;
    ushort_t* Al0 = &As[(wave * 32) * 32];
    ushort_t* Al1 = &As[(wave * 32 + 16) * 32];
    ushort_t* Wl0 = &Ws[(wave * 32) * 32];
    ushort_t* Wl1 = &Ws[(wave * 32 + 16) * 32];

    const int fr   = lane & 15;      // fragment row(A)/col(B)
    const int quad = lane >> 4;

    for (int k0 = 0; k0 < K; k0 += 32) {
        gload_lds16(Ag0 + k0, Al0);
        gload_lds16(Ag1 + k0, Al1);
        gload_lds16(Wg0 + k0, Wl0);
        gload_lds16(Wg1 + k0, Wl1);
        __syncthreads();
        short8 af[4], wf[4];
#pragma unroll
        for (int i = 0; i < 4; i++)
            af[i] = *(const short8*)&As[(wm * 64 + i * 16 + fr) * 32 + quad * 8];
#pragma unroll
        for (int j = 0; j < 4; j++)
            wf[j] = *(const short8*)&Ws[(wn * 64 + j * 16 + fr) * 32 + quad * 8];
#pragma unroll
        for (int i = 0; i < 4; i++)
#pragma unroll
            for (int j = 0; j < 4; j++)
                acc[i][j] = __builtin_amdgcn_mfma_f32_16x16x32_bf16(
                    af[i], wf[j], acc[i][j], 0, 0, 0);
        __syncthreads();
    }

    // C/D layout: col = lane&15, row = quad*4 + reg (per 16x16 frag)
    if (MODE == 3) {
#pragma unroll
        for (int i = 0; i < 4; i++)
#pragma unroll
            for (int r = 0; r < 4; r++) {
                int row = m0 + wm * 64 + i * 16 + quad * 4 + r;
                float part = 0.f;
#pragma unroll
                for (int j = 0; j < 4; j++) {
                    int col = n0 + wn * 64 + j * 16 + fr;
                    float v = fmaxf(acc[i][j][r] + bias[col], 0.f);
                    part = fmaf(v, OW[col], part);
                }
                part += __shfl_xor(part, 1, 64);
                part += __shfl_xor(part, 2, 64);
                part += __shfl_xor(part, 4, 64);
                part += __shfl_xor(part, 8, 64);
                if (fr == 0) atomicAdd(&lg[row], part);
            }
        return;
    }

    const int nbase = n0 + wn * 64;
    bool side = (MODE == 5) && (nbase >= 512);
    const float* bp = side ? bias2 : bias;
    const int boff  = (MODE == 5) ? (nbase & 511) : nbase;
    const float scl = (MODE == 5 && !side) ? 0.125f : 1.f;

    // stage bf16 tile into wave-private LDS (no barrier needed)
#pragma unroll
    for (int i = 0; i < 4; i++)
#pragma unroll
        for (int r = 0; r < 4; r++) {
            int rl = i * 16 + quad * 4 + r;          // row local 0..63
#pragma unroll
            for (int j = 0; j < 4; j++) {
                int cl = j * 16 + fr;                // col local 0..63
                float v = (acc[i][j][r] + bp[boff + cl]) * scl;
                if (RELU) v = fmaxf(v, 0.f);
                if (MODE == 4) et[wave][cl][rl] = f2bf(v);
                else           et[wave][rl][cl] = f2bf(v);
            }
        }

    // coalesced readback + store: 8 lanes per stage-row -> 128B runs
    const int sub8 = (lane & 7) * 8;
    const int grp  = lane >> 3;                      // 0..7
#pragma unroll
    for (int rr = 0; rr < 8; rr++) {
        int rowl = rr * 8 + grp;                     // stage row 0..63
        short8 val = *(const short8*)&et[wave][rowl][sub8];
        if (MODE == 1) {
            int row = m0 + wm * 64 + rowl;
            int col = nbase + sub8;
            *(short8*)&Cb[(size_t)row * ldc + col] = val;
        } else if (MODE == 5) {
            int row = m0 + wm * 64 + rowl;           // t*32 + b
            int t = row >> 5, b = row & 31;
            int h = (nbase >> 6) & 7;
            ushort_t* base = side ? Cb2 : Cb;
            *(short8*)&base[(((size_t)(b * 8 + h)) << 15) + ((size_t)t << 6) + sub8] = val;
        } else { // MODE 4: stage row = output col (d), stage col = m (b*512+t)
            int m = m0 + wm * 64 + sub8;             // 8 consecutive t, same b
            int b = m >> 9, t = m & 511;
            int h = nbase >> 6;
            int d = rowl;
            *(short8*)&Cb[(((size_t)(b * 8 + h)) << 15) + ((size_t)d << 9) + t] = val;
        }
    }
}

// ---------------------------------------------------------------------------
// MFMA flash attention, no-rescale softmax. grid=(B*NH, 8 rev q-tiles), 256thr
// qb (pre-scaled by 1/8), kb: bf16 [bh][t][64]; vtb: bf16 [bh][d][512].
// p = exp2(fma(s, decay*log2e, mneg)); l via MFMA with ones-B.
// ---------------------------------------------------------------------------
__global__ __launch_bounds__(256) void attn_mfma(
    const ushort_t* __restrict__ qb, const ushort_t* __restrict__ kb,
    const ushort_t* __restrict__ vtb, const float* __restrict__ mask,
    const float* __restrict__ gammas, ushort_t* __restrict__ attnc)
{
    __shared__ __align__(16) ushort_t ps[4][16][72];   // P / O stage, per wave
    __shared__ __align__(16) float4 decay4[512];       // replicated LUT
    __shared__ float decayF[512];
    __shared__ float mneg[512];

    const int bh  = blockIdx.x;          // b*8 + h
    const int b   = bh >> 3;
    const int h   = bh & 7;
    const int qt0 = (7 - blockIdx.y) * 64;   // heavy tiles first
    const int tid  = threadIdx.x;
    const int wave = tid >> 6;
    const int lane = tid & 63;
    const int fr   = lane & 15;
    const int quad = lane >> 4;

    {   // LUTs: decay' = clip(exp(-sp*sqrt(d)),1e-5,..)*log2e ; mneg = 0/-1e32
        float g  = gammas[h];
        float sp = (g > 20.f) ? g : log1pf(expf(g));
        float* dtmp = (float*)ps;        // scratch (515 floats fit in ps[0])
        for (int i = tid; i < 515; i += 256) {
            int d = i < 511 ? i : 511;
            dtmp[i] = fmaxf(exp2f(-sp * 1.44269504f * sqrtf((float)d)), 1e-5f)
                      * 1.44269504f;
        }
        for (int i = tid; i < 512; i += 256)
            mneg[i] = (mask[(size_t)i * B_SZ + b] == 0.f) ? -1e32f : 0.f;
        __syncthreads();
        for (int i = tid; i < 512; i += 256) {
            decay4[i] = make_float4(dtmp[i], dtmp[i+1], dtmp[i+2], dtmp[i+3]);
        }
        __syncthreads();                 // dtmp (in ps) dead after this
        for (int i = tid; i < 512; i += 256)
            decayF[i] = decay4[i].x;
        __syncthreads();
    }

    const int qr0 = qt0 + wave * 16;
    const ushort_t* qbase = qb  + ((size_t)bh << 15);   // [t][64]
    const ushort_t* kbase = kb  + ((size_t)bh << 15);
    const ushort_t* vbase = vtb + ((size_t)bh << 15);   // [d][512]

    short8 af0 = *(const short8*)(qbase + (size_t)(qr0 + fr) * 64 + quad * 8);
    short8 af1 = *(const short8*)(qbase + (size_t)(qr0 + fr) * 64 + 32 + quad * 8);
    const short8 ones = {0x3F80, 0x3F80, 0x3F80, 0x3F80,
                         0x3F80, 0x3F80, 0x3F80, 0x3F80};

    f32x4 o[4] = {};                    // O[q=quad*4+r][d=j2*16+fr]
    f32x4 lacc = {};                    // row sums, same layout rows

    auto tile = [&](int kt0, bool diag) {
        f32x4 sacc[4] = {};
#pragma unroll
        for (int j = 0; j < 4; j++) {
            const ushort_t* kr = kbase + (size_t)(kt0 + j * 16 + fr) * 64;
            short8 k0 = *(const short8*)(kr + quad * 8);
            short8 k1 = *(const short8*)(kr + 32 + quad * 8);
            sacc[j] = __builtin_amdgcn_mfma_f32_16x16x32_bf16(af0, k0, sacc[j], 0, 0, 0);
            sacc[j] = __builtin_amdgcn_mfma_f32_16x16x32_bf16(af1, k1, sacc[j], 0, 0, 0);
        }
#pragma unroll
        for (int j = 0; j < 4; j++) {
            int kg = kt0 + j * 16 + fr;
            float mn = mneg[kg];
            int qgb = qr0 + quad * 4;
            if (!diag) {
                float4 dv = decay4[qgb - kg];
                float dvv[4] = {dv.x, dv.y, dv.z, dv.w};
#pragma unroll
                for (int r = 0; r < 4; r++) {
                    float t = fmaf(sacc[j][r], dvv[r], mn);
                    union { float f; unsigned u; } cv; cv.f = exp2f(t);
                    ps[wave][quad * 4 + r][j * 16 + fr] = (ushort_t)(cv.u >> 16);
                }
            } else {
#pragma unroll
                for (int r = 0; r < 4; r++) {
                    int didx = qgb + r - kg;
                    float dec = decayF[didx > 0 ? didx : 0];
                    float t = fmaf(sacc[j][r], dec, mn);
                    if (didx <= 0) t = -1e32f;      // causal (kg >= qg)
                    union { float f; unsigned u; } cv; cv.f = exp2f(t);
                    ps[wave][quad * 4 + r][j * 16 + fr] = (ushort_t)(cv.u >> 16);
                }
            }
        }
        short8 pf0 = *(const short8*)&ps[wave][fr][quad * 8];
        short8 pf1 = *(const short8*)&ps[wave][fr][32 + quad * 8];
        lacc = __builtin_amdgcn_mfma_f32_16x16x32_bf16(pf0, ones, lacc, 0, 0, 0);
        lacc = __builtin_amdgcn_mfma_f32_16x16x32_bf16(pf1, ones, lacc, 0, 0, 0);
#pragma unroll
        for (int j2 = 0; j2 < 4; j2++) {
            const ushort_t* vr = vbase + (size_t)(j2 * 16 + fr) * T_LEN + kt0;
            short8 v0 = *(const short8*)(vr + quad * 8);
            short8 v1 = *(const short8*)(vr + 32 + quad * 8);
            o[j2] = __builtin_amdgcn_mfma_f32_16x16x32_bf16(pf0, v0, o[j2], 0, 0, 0);
            o[j2] = __builtin_amdgcn_mfma_f32_16x16x32_bf16(pf1, v1, o[j2], 0, 0, 0);
        }
    };

    for (int kt0 = 0; kt0 < qt0; kt0 += 64) tile(kt0, false);
    tile(qt0, true);

    // epilogue: divide by l, zero row q==0, stage + coalesced store
#pragma unroll
    for (int r = 0; r < 4; r++) {
        int qg = qr0 + quad * 4 + r;
        float linv = (qg == 0) ? 0.f : 1.f / lacc[r];
#pragma unroll
        for (int j2 = 0; j2 < 4; j2++)
            ps[wave][quad * 4 + r][j2 * 16 + fr] = f2bf(o[j2][r] * linv);
    }
    const int sub8 = (lane & 7) * 8;
    const int grp  = lane >> 3;
#pragma unroll
    for (int half = 0; half < 2; half++) {
        int rowl = half * 8 + grp;                   // 0..15
        short8 val = *(const short8*)&ps[wave][rowl][sub8];
        int qg = qr0 + rowl;
        *(short8*)&attnc[((size_t)qg * B_SZ + b) * H_DIM + h * DHEAD + sub8] = val;
    }
}

// ---------------------------------------------------------------------------
// LN1: reads bf16 X, writes out1 fp32 + bf16
// ---------------------------------------------------------------------------
__global__ __launch_bounds__(256) void ln1_kernel(
    const ushort_t* __restrict__ X, const float* __restrict__ g,
    const float* __restrict__ bta, float* __restrict__ Y,
    ushort_t* __restrict__ Yb)
{
    int m    = blockIdx.x * 4 + (threadIdx.x >> 6);
    int lane = threadIdx.x & 63;
    int c0   = lane * 8;
    const ushort_t* xr = X + (size_t)m * H_DIM + c0;
    float x[8];
    float s = 0.f, ss = 0.f;
    short8 xv = *(const short8*)xr;
#pragma unroll
    for (int i = 0; i < 8; i++) {
        x[i] = bf2f((ushort_t)xv[i]);
        s += x[i]; ss += x[i] * x[i];
    }
#pragma unroll
    for (int off = 32; off >= 1; off >>= 1) {
        s  += __shfl_xor(s,  off, 64);
        ss += __shfl_xor(ss, off, 64);
    }
    float mu  = s * (1.f / 512.f);
    float var = ss * (1.f / 512.f) - mu * mu;
    float rs  = rsqrtf(var + 1e-5f);
    float  yo[8];
    ushort_t yb[8];
#pragma unroll
    for (int i = 0; i < 8; i++) {
        float v = (x[i] - mu) * rs * g[c0 + i] + bta[c0 + i];
        yo[i] = v; yb[i] = f2bf(v);
    }
    *(float4*)(Y + (size_t)m * H_DIM + c0)     = *(float4*)&yo[0];
    *(float4*)(Y + (size_t)m * H_DIM + c0 + 4) = *(float4*)&yo[4];
    *(short8*)(Yb + (size_t)m * H_DIM + c0)    = *(short8*)&yb[0];
}

// ---------------------------------------------------------------------------
// LN2 + residual + fused OW-dot: pred_bf[:,0:512] = bf16(out1 + LN(f2));
// lgits[m] += dot(fp32 row values, OW[0:512])
// ---------------------------------------------------------------------------
__global__ __launch_bounds__(256) void ln2_kernel(
    const ushort_t* __restrict__ X, const float* __restrict__ g,
    const float* __restrict__ bta, const float* __restrict__ res,
    ushort_t* __restrict__ pred_bf, const float* __restrict__ OW,
    float* __restrict__ lg)
{
    int m    = blockIdx.x * 4 + (threadIdx.x >> 6);
    int lane = threadIdx.x & 63;
    int c0   = lane * 8;
    const ushort_t* xr = X + (size_t)m * H_DIM + c0;
    float x[8];
    float s = 0.f, ss = 0.f;
    short8 xv = *(const short8*)xr;
#pragma unroll
    for (int i = 0; i < 8; i++) {
        x[i] = bf2f((ushort_t)xv[i]);
        s += x[i]; ss += x[i] * x[i];
    }
#pragma unroll
    for (int off = 32; off >= 1; off >>= 1) {
        s  += __shfl_xor(s,  off, 64);
        ss += __shfl_xor(ss, off, 64);
    }
    float mu  = s * (1.f / 512.f);
    float var = ss * (1.f / 512.f) - mu * mu;
    float rs  = rsqrtf(var + 1e-5f);
    float4 r0 = *(const float4*)(res + (size_t)m * H_DIM + c0);
    float4 r1 = *(const float4*)(res + (size_t)m * H_DIM + c0 + 4);
    float rr[8] = {r0.x, r0.y, r0.z, r0.w, r1.x, r1.y, r1.z, r1.w};
    ushort_t yb[8];
    float part = 0.f;
#pragma unroll
    for (int i = 0; i < 8; i++) {
        float v = (x[i] - mu) * rs * g[c0 + i] + bta[c0 + i] + rr[i];
        yb[i] = f2bf(v);
        part = fmaf(v, OW[c0 + i], part);
    }
    *(short8*)(pred_bf + (size_t)m * P_DIM + c0) = *(short8*)&yb[0];
#pragma unroll
    for (int off = 32; off >= 1; off >>= 1) part += __shfl_xor(part, off, 64);
    if (lane == 0) lg[m] += part;
}

// ---------------------------------------------------------------------------
// predot_early: lg[row] = Ob + dot(pred_bf[row, 512:1152], OW[512:]); zero accum
// ---------------------------------------------------------------------------
__global__ __launch_bounds__(256) void predot_early(
    const ushort_t* __restrict__ pred_bf, const float* __restrict__ OW,
    const float* __restrict__ Ob, float* __restrict__ lg,
    float* __restrict__ accum)
{
    if (blockIdx.x == 0 && threadIdx.x < 2) accum[threadIdx.x] = 0.f;
    int m    = blockIdx.x * 4 + (threadIdx.x >> 6);
    int lane = threadIdx.x & 63;
    const ushort_t* pr = pred_bf + (size_t)m * P_DIM;
    float s = 0.f;
#pragma unroll 5
    for (int c = 512 + lane; c < P_DIM; c += 64)
        s = fmaf(bf2f(pr[c]), OW[c], s);
#pragma unroll
    for (int off = 32; off >= 1; off >>= 1) s += __shfl_xor(s, off, 64);
    if (lane == 0) lg[m] = s + Ob[0];
}

// ---------------------------------------------------------------------------
__global__ __launch_bounds__(256) void bce_kernel(
    const float* __restrict__ lg, const int* __restrict__ labels,
    const float* __restrict__ mask, float* __restrict__ accum)
{
    int m    = blockIdx.x * 256 + threadIdx.x;
    int lane = threadIdx.x & 63;
    float l  = lg[m];
    float y  = (float)labels[m];
    float mv = mask[m];
    float a  = (fmaxf(l, 0.f) - l * y + log1pf(expf(-fabsf(l)))) * mv;
#pragma unroll
    for (int off = 32; off >= 1; off >>= 1) {
        a  += __shfl_xor(a,  off, 64);
        mv += __shfl_xor(mv, off, 64);
    }
    if (lane == 0) {
        atomicAdd(accum,     a);
        atomicAdd(accum + 1, mv);
    }
}

__global__ void finalize_kernel(const float* __restrict__ accum, float* __restrict__ out)
{
    out[0] = accum[0] / accum[1];
}

// ---------------------------------------------------------------------------
extern "C" void kernel_launch(void* const* d_in, const int* in_sizes, int n_in,
                              void* d_out, int out_size, void* d_ws, size_t ws_size,
                              hipStream_t stream)
{
    (void)in_sizes; (void)n_in; (void)out_size;
    const int*   ans    = (const int*)  d_in[0];
    const int*   cans   = (const int*)  d_in[1];
    const int*   labels = (const int*)  d_in[2];
    const float* mask   = (const float*)d_in[3];
    const int*   qids   = (const int*)  d_in[4];
    const int*   sids   = (const int*)  d_in[5];
    const float* smask  = (const float*)d_in[6];
    const float* Eq     = (const float*)d_in[7];
    const float* Es     = (const float*)d_in[8];
    const float* Ea     = (const float*)d_in[9];
    const float* El     = (const float*)d_in[10];
    const float* Wq     = (const float*)d_in[11];
    const float* bq     = (const float*)d_in[12];
    const float* Wk     = (const float*)d_in[13];
    const float* bk     = (const float*)d_in[14];
    const float* Wv     = (const float*)d_in[15];
    const float* bv     = (const float*)d_in[16];
    const float* Wo     = (const float*)d_in[17];
    const float* bo     = (const float*)d_in[18];
    const float* ln1_g  = (const float*)d_in[19];
    const float* ln1_b  = (const float*)d_in[20];
    const float* W1     = (const float*)d_in[21];
    const float* b1     = (const float*)d_in[22];
    const float* W2     = (const float*)d_in[23];
    const float* b2     = (const float*)d_in[24];
    const float* ln2_g  = (const float*)d_in[25];
    const float* ln2_b  = (const float*)d_in[26];
    const float* gammas = (const float*)d_in[27];
    const float* L1W    = (const float*)d_in[28];
    const float* L1b    = (const float*)d_in[29];
    const float* L2W    = (const float*)d_in[30];
    const float* L2b    = (const float*)d_in[31];
    const float* OW     = (const float*)d_in[32];
    const float* Ob     = (const float*)d_in[33];
    float* out = (float*)d_out;

    // Arena in units U = TB*64 floats (4 MiB). Peak 42U ≈ 176 MB.
    const size_t U = (size_t)TBTOK * 64;
    if (ws_size < 42 * U * sizeof(float)) return;
    float* ws = (float*)d_ws;
    ushort_t* wtb      = (ushort_t*)(ws);            // [0,3)  weights bf16 (perm)
    ushort_t* pred_bf  = (ushort_t*)(ws + 3 * U);    // [3,12) perm
    ushort_t* value_bf = (ushort_t*)(ws + 12 * U);   // [12,21) until V-gemm
    ushort_t* qb       = (ushort_t*)(ws + 21 * U);   // [21,25) until attn
    ushort_t* kb       = (ushort_t*)(ws + 25 * U);   // [25,29) until attn
    ushort_t* vtb      = (ushort_t*)(ws + 29 * U);   // [29,33) until attn
    ushort_t* attnc_bf = (ushort_t*)(ws + 33 * U);   // [33,37) until Wo
    ushort_t* x1_bf    = (ushort_t*)(ws + 12 * U);   // [12,16) Wo-out / LN1-in
    float*    out1     = ws + 16 * U;                // [16,24) LN1..LN2 fp32
    ushort_t* out1_bf  = (ushort_t*)(ws + 24 * U);   // [24,28)
    ushort_t* f1_bf    = (ushort_t*)(ws + 28 * U);   // [28,32) W1-out
    ushort_t* f2_bf    = (ushort_t*)(ws + 32 * U);   // [32,36) W2-out / LN2-in
    ushort_t* h1_bf    = (ushort_t*)(ws + 12 * U);   // [12,21) L1-out
    float*    lgits    = ws + 41 * U;                // TB floats
    float*    accum    = lgits + TBTOK;

    // bf16 weight arena offsets (elements); wq||wk contiguous for merged QK
    ushort_t* wqk_b = wtb + 0;         // 1024 x 640
    ushort_t* wv_b  = wtb + 655360;
    ushort_t* wo_b  = wtb + 1245184;
    ushort_t* w1_b  = wtb + 1507328;
    ushort_t* w2_b  = wtb + 1769472;
    ushort_t* l1_b  = wtb + 2031616;
    ushort_t* l2_b  = wtb + 3358720;

    convert_weights<<<4576, 256, 0, stream>>>(Wq, Wk, Wv, Wo, W1, W2, L1W, L2W, wtb);
    embed_kernel<<<TBTOK, 256, 0, stream>>>(ans, cans, labels, mask, qids, sids,
                                            smask, Eq, Es, Ea, El, pred_bf, value_bf);
    // logits tail dot (static cols) + accum zero
    predot_early<<<TBTOK/4, 256, 0, stream>>>(pred_bf, OW, Ob, lgits, accum);
    // merged Q|K projection (Q pre-scaled by 1/8), then V^T
    mgemm<5,false><<<dim3(TBTOK/128, 8), 256, 0, stream>>>(
        pred_bf + 512, P_DIM, wqk_b, 640, bq, bk, qb, kb, 0, 640, nullptr, nullptr);
    mgemm<4,false><<<dim3(TBTOK/128, 4), 256, 0, stream>>>(
        value_bf, P_DIM, wv_b, P_DIM, bv, nullptr, vtb, nullptr, 0, P_DIM, nullptr, nullptr);
    // attention (MFMA flash, no-rescale softmax)
    attn_mfma<<<dim3(B_SZ * NHEAD, 8), 256, 0, stream>>>(
        qb, kb, vtb, mask, gammas, attnc_bf);
    // output projection -> x1_bf
    mgemm<1,false><<<dim3(TBTOK/128, 4), 256, 0, stream>>>(
        attnc_bf, H_DIM, wo_b, H_DIM, bo, nullptr, x1_bf, nullptr, H_DIM, H_DIM, nullptr, nullptr);
    ln1_kernel<<<TBTOK/4, 256, 0, stream>>>(x1_bf, ln1_g, ln1_b, out1, out1_bf);
    // FFN
    mgemm<1,true><<<dim3(TBTOK/128, 4), 256, 0, stream>>>(
        out1_bf, H_DIM, w1_b, H_DIM, b1, nullptr, f1_bf, nullptr, H_DIM, H_DIM, nullptr, nullptr);
    mgemm<1,false><<<dim3(TBTOK/128, 4), 256, 0, stream>>>(
        f1_bf, H_DIM, w2_b, H_DIM, b2, nullptr, f2_bf, nullptr, H_DIM, H_DIM, nullptr, nullptr);
    // LN2 + residual + fused head-dot into lgits
    ln2_kernel<<<TBTOK/4, 256, 0, stream>>>(f2_bf, ln2_g, ln2_b, out1, pred_bf, OW, lgits);
    // L1 (relu)
    mgemm<1,true><<<dim3(TBTOK/128, 9), 256, 0, stream>>>(
        pred_bf, P_DIM, l1_b, P_DIM, L1b, nullptr, h1_bf, nullptr, P_DIM, P_DIM, nullptr, nullptr);
    // L2 (relu) fused with OW dot -> atomics into lgits
    mgemm<3,true><<<dim3(TBTOK/128, 9), 256, 0, stream>>>(
        h1_bf, P_DIM, l2_b, P_DIM, L2b, nullptr, nullptr, nullptr, 0, P_DIM, OW, lgits);
    // BCE + reduction
    bce_kernel<<<TBTOK/256, 256, 0, stream>>>(lgits, labels, mask, accum);
    finalize_kernel<<<1, 1, 0, stream>>>(accum, out);
}